// Round 1
// baseline (521.918 us; speedup 1.0000x reference)
//
#include <hip/hip_runtime.h>

#define Bq 8
#define Cq 256
#define Hq 64
#define Wq 64
#define Nq 4096        // H*W
#define HEADSq 8
#define DIMq 32
#define NCq 256        // compressed tokens 16*16
#define TOPKq 64
#define BHq 64
#define SCALEq 0.17677669529663687f   // 32^-0.5

// ---------------- K1: fused q/k/v 1x1 conv (3 GEMMs sharing x tiles) -------
__global__ __launch_bounds__(256) void qkv_proj(
    const float* __restrict__ x,
    const float* __restrict__ wq, const float* __restrict__ wk, const float* __restrict__ wv,
    float* __restrict__ q, float* __restrict__ kf, float* __restrict__ vf) {
  const int b  = blockIdx.z;
  const int o0 = blockIdx.y * 64;
  const int n0 = blockIdx.x * 64;
  __shared__ float xs[16][64];
  __shared__ float wqs[16][64], wks[16][64], wvs[16][64];
  const int t = threadIdx.x;
  const int tn = t & 15;    // n sub-index
  const int to = t >> 4;    // o group
  float accq[4][4] = {}, acck[4][4] = {}, accv[4][4] = {};
  const float* xb = x + (size_t)b * Cq * Nq;
  for (int c0 = 0; c0 < Cq; c0 += 16) {
    __syncthreads();
#pragma unroll
    for (int i = 0; i < 4; ++i) {
      int idx = t + i * 256;
      int cc = idx >> 6, j = idx & 63;
      xs[cc][j] = xb[(size_t)(c0 + cc) * Nq + n0 + j];
    }
#pragma unroll
    for (int i = 0; i < 4; ++i) {
      int idx = t + i * 256;
      int cc = idx & 15, o = idx >> 4;
      wqs[cc][o] = wq[(o0 + o) * Cq + c0 + cc];
      wks[cc][o] = wk[(o0 + o) * Cq + c0 + cc];
      wvs[cc][o] = wv[(o0 + o) * Cq + c0 + cc];
    }
    __syncthreads();
#pragma unroll
    for (int cc = 0; cc < 16; ++cc) {
      float a[4];
#pragma unroll
      for (int i = 0; i < 4; ++i) a[i] = xs[cc][tn + 16 * i];
#pragma unroll
      for (int j = 0; j < 4; ++j) {
        float bq = wqs[cc][to * 4 + j];
        float bk = wks[cc][to * 4 + j];
        float bv = wvs[cc][to * 4 + j];
#pragma unroll
        for (int i = 0; i < 4; ++i) {
          accq[j][i] += bq * a[i];
          acck[j][i] += bk * a[i];
          accv[j][i] += bv * a[i];
        }
      }
    }
  }
#pragma unroll
  for (int j = 0; j < 4; ++j) {
    int o = o0 + to * 4 + j;
    size_t base = ((size_t)b * Cq + o) * Nq + n0 + tn;
#pragma unroll
    for (int i = 0; i < 4; ++i) {
      q[base + 16 * i]  = accq[j][i];
      kf[base + 16 * i] = acck[j][i];
      vf[base + 16 * i] = accv[j][i];
    }
  }
}

// ---------------- K2: depthwise 4x4 non-overlapping pooling ---------------
__global__ __launch_bounds__(256) void pool_kv(
    const float* __restrict__ kf, const float* __restrict__ vf,
    const float* __restrict__ wck, const float* __restrict__ wcv,
    float* __restrict__ ks, float* __restrict__ vs) {
  int bc = blockIdx.x;
  int b = bc / Cq, c = bc % Cq;
  int t = threadIdx.x;
  int i = t >> 4, j = t & 15;
  const float* kp = kf + ((size_t)b * Cq + c) * Nq;
  const float* vp = vf + ((size_t)b * Cq + c) * Nq;
  __shared__ float wk_s[16], wv_s[16];
  if (t < 16) { wk_s[t] = wck[c * 16 + t]; wv_s[t] = wcv[c * 16 + t]; }
  __syncthreads();
  float ak = 0.f, av = 0.f;
#pragma unroll
  for (int r = 0; r < 4; ++r)
#pragma unroll
    for (int s = 0; s < 4; ++s) {
      int n = (i * 4 + r) * Wq + j * 4 + s;
      float wkv = wk_s[r * 4 + s], wvv = wv_s[r * 4 + s];
      ak += kp[n] * wkv;
      av += vp[n] * wvv;
    }
  ks[((size_t)b * Cq + c) * NCq + t] = ak;
  vs[((size_t)b * Cq + c) * NCq + t] = av;
}

// ---------------- K3a: stage-1 softmax column-sum (token scores) ----------
// grid (chunk=8, bh=64); block 256 = 4 waves; each block does 512 query rows.
__global__ __launch_bounds__(256) void stage1_scores(
    const float* __restrict__ q, const float* __restrict__ ks,
    float* __restrict__ part) {
  const int bh = blockIdx.y;
  const int b = bh >> 3, h = bh & 7;
  const int row0 = blockIdx.x * 512;
  const int t = threadIdx.x;
  const int wave = t >> 6, lane = t & 63;
  __shared__ float kt[DIMq][NCq];       // 32 KB, [d][tok]
  __shared__ float qs[64][DIMq + 1];    // [row][d]
  __shared__ float sc[4][NCq];          // per-wave score accum

  const float* ksb = ks + ((size_t)b * Cq + h * DIMq) * NCq;
  for (int idx = t; idx < DIMq * NCq; idx += 256) {
    int d = idx >> 8, tok = idx & 255;
    kt[d][tok] = ksb[(size_t)d * NCq + tok];
  }
  for (int tok = t; tok < NCq; tok += 256) {
    sc[0][tok] = 0.f; sc[1][tok] = 0.f; sc[2][tok] = 0.f; sc[3][tok] = 0.f;
  }
  const float4* ktv = (const float4*)&kt[0][0];  // ktv[d*64 + lane] = kt[d][4*lane..]
  const float* qb = q + ((size_t)b * Cq + h * DIMq) * Nq;

  for (int ch = 0; ch < 8; ++ch) {
    int r0 = row0 + ch * 64;
    __syncthreads();   // orders sc-init / prior qs reads before overwrite
    for (int idx = t; idx < 64 * DIMq; idx += 256) {
      int d = idx >> 6, r = idx & 63;
      qs[r][d] = qb[(size_t)d * Nq + r0 + r];
    }
    __syncthreads();
    for (int rr = 0; rr < 16; rr += 4) {
      int r = wave * 16 + rr;
      float lg[4][4] = {};
#pragma unroll
      for (int d = 0; d < DIMq; ++d) {
        float4 kv = ktv[d * 64 + lane];
        float qv[4];
#pragma unroll
        for (int i = 0; i < 4; ++i) qv[i] = qs[r + i][d];
#pragma unroll
        for (int i = 0; i < 4; ++i) {
          lg[i][0] += qv[i] * kv.x;
          lg[i][1] += qv[i] * kv.y;
          lg[i][2] += qv[i] * kv.z;
          lg[i][3] += qv[i] * kv.w;
        }
      }
#pragma unroll
      for (int i = 0; i < 4; ++i) {
        float l0 = lg[i][0] * SCALEq, l1 = lg[i][1] * SCALEq;
        float l2 = lg[i][2] * SCALEq, l3 = lg[i][3] * SCALEq;
        float m = fmaxf(fmaxf(l0, l1), fmaxf(l2, l3));
        for (int off = 32; off; off >>= 1) m = fmaxf(m, __shfl_xor(m, off));
        float e0 = __expf(l0 - m), e1 = __expf(l1 - m);
        float e2 = __expf(l2 - m), e3 = __expf(l3 - m);
        float s = e0 + e1 + e2 + e3;
        for (int off = 32; off; off >>= 1) s += __shfl_xor(s, off);
        float inv = 1.0f / s;
        sc[wave][lane * 4 + 0] += e0 * inv;
        sc[wave][lane * 4 + 1] += e1 * inv;
        sc[wave][lane * 4 + 2] += e2 * inv;
        sc[wave][lane * 4 + 3] += e3 * inv;
      }
    }
  }
  __syncthreads();
  for (int tok = t; tok < NCq; tok += 256) {
    float v = sc[0][tok] + sc[1][tok] + sc[2][tok] + sc[3][tok];
    part[((size_t)bh * 8 + blockIdx.x) * NCq + tok] = v;
  }
}

// ---------------- K3b: reduce partial scores ------------------------------
__global__ __launch_bounds__(256) void reduce_scores(
    const float* __restrict__ part, float* __restrict__ score) {
  int bh = blockIdx.x, t = threadIdx.x;
  float s = 0.f;
#pragma unroll
  for (int c = 0; c < 8; ++c) s += part[((size_t)bh * 8 + c) * NCq + t];
  score[bh * NCq + t] = s;
}

// ---------------- K4: exact stable top-64 (rank = count of strictly-greater
// plus equal-with-lower-index; matches jax.lax.top_k ordering) -------------
__global__ __launch_bounds__(256) void topk_sel(
    const float* __restrict__ score, int* __restrict__ idx) {
  int bh = blockIdx.x, t = threadIdx.x;
  __shared__ float s[NCq];
  s[t] = score[bh * NCq + t];
  __syncthreads();
  float st = s[t];
  int rank = 0;
  for (int j = 0; j < NCq; ++j) {
    float sj = s[j];
    rank += (sj > st) || (sj == st && j < t);
  }
  if (rank < TOPKq) idx[bh * TOPKq + rank] = t;
}

// ---------------- K5: stage-2 attention over selected tokens --------------
// grid (rowchunk=64, bh=64); block 256; 64 query rows per block.
__global__ __launch_bounds__(256) void stage2_attn(
    const float* __restrict__ q, const float* __restrict__ ks,
    const float* __restrict__ vs, const int* __restrict__ idx,
    float* __restrict__ out) {
  const int bh = blockIdx.y, b = bh >> 3, h = bh & 7;
  const int n0 = blockIdx.x * 64;
  const int t = threadIdx.x;
  __shared__ float kt[DIMq][TOPKq];
  __shared__ float vt[DIMq][TOPKq];
  __shared__ float qs[DIMq][64];
  __shared__ float L[64][TOPKq + 1];
  const float* ksb = ks + ((size_t)b * Cq + h * DIMq) * NCq;
  const float* vsb = vs + ((size_t)b * Cq + h * DIMq) * NCq;
  const int* ib = idx + bh * TOPKq;
  for (int e = t; e < DIMq * TOPKq; e += 256) {
    int d = e >> 6, j = e & 63;
    int tok = ib[j];
    kt[d][j] = ksb[(size_t)d * NCq + tok];
    vt[d][j] = vsb[(size_t)d * NCq + tok];
  }
  const float* qb = q + ((size_t)b * Cq + h * DIMq) * Nq;
  for (int e = t; e < DIMq * 64; e += 256) {
    int d = e >> 6, r = e & 63;
    qs[d][r] = qb[(size_t)d * Nq + n0 + r];
  }
  __syncthreads();
  {  // phase A: logits [64 rows][64 toks]
    int r = t & 63;
    int tg = (t >> 6) * 16;
    float acc[16];
#pragma unroll
    for (int j = 0; j < 16; ++j) acc[j] = 0.f;
    for (int d = 0; d < DIMq; ++d) {
      float qd = qs[d][r];
#pragma unroll
      for (int j = 0; j < 16; ++j) acc[j] += qd * kt[d][tg + j];
    }
#pragma unroll
    for (int j = 0; j < 16; ++j) L[r][tg + j] = acc[j] * SCALEq;
  }
  __syncthreads();
  if (t < 64) {  // phase B: row softmax
    float m = -1e30f;
    for (int j = 0; j < TOPKq; ++j) m = fmaxf(m, L[t][j]);
    float s = 0.f;
    for (int j = 0; j < TOPKq; ++j) { float e = __expf(L[t][j] - m); L[t][j] = e; s += e; }
    float inv = 1.0f / s;
    for (int j = 0; j < TOPKq; ++j) L[t][j] *= inv;
  }
  __syncthreads();
  {  // phase C: out = attn @ v_top^T
    int r = t & 63;
    int d0 = (t >> 6) * 8;
    float acc[8] = {};
    for (int j = 0; j < TOPKq; ++j) {
      float a = L[r][j];
#pragma unroll
      for (int dd = 0; dd < 8; ++dd) acc[dd] += a * vt[d0 + dd][j];
    }
#pragma unroll
    for (int dd = 0; dd < 8; ++dd)
      out[((size_t)b * Cq + h * DIMq + d0 + dd) * Nq + n0 + r] = acc[dd];
  }
}

// ---------------- K6: output 1x1 conv + bias ------------------------------
__global__ __launch_bounds__(256) void out_proj(
    const float* __restrict__ a, const float* __restrict__ wo,
    const float* __restrict__ bo, float* __restrict__ y) {
  const int b = blockIdx.z, o0 = blockIdx.y * 64, n0 = blockIdx.x * 64;
  __shared__ float xs[16][64], wsp[16][64];
  const int t = threadIdx.x, tn = t & 15, to = t >> 4;
  float acc[4][4] = {};
  const float* ab = a + (size_t)b * Cq * Nq;
  for (int c0 = 0; c0 < Cq; c0 += 16) {
    __syncthreads();
#pragma unroll
    for (int i = 0; i < 4; ++i) {
      int idx = t + i * 256, cc = idx >> 6, j = idx & 63;
      xs[cc][j] = ab[(size_t)(c0 + cc) * Nq + n0 + j];
    }
#pragma unroll
    for (int i = 0; i < 4; ++i) {
      int idx = t + i * 256, cc = idx & 15, o = idx >> 4;
      wsp[cc][o] = wo[(o0 + o) * Cq + c0 + cc];
    }
    __syncthreads();
#pragma unroll
    for (int cc = 0; cc < 16; ++cc) {
      float av[4];
#pragma unroll
      for (int i = 0; i < 4; ++i) av[i] = xs[cc][tn + 16 * i];
#pragma unroll
      for (int j = 0; j < 4; ++j) {
        float wv = wsp[cc][to * 4 + j];
#pragma unroll
        for (int i = 0; i < 4; ++i) acc[j][i] += wv * av[i];
      }
    }
  }
#pragma unroll
  for (int j = 0; j < 4; ++j) {
    int o = o0 + to * 4 + j;
    float bias = bo[o];
    size_t base = ((size_t)b * Cq + o) * Nq + n0 + tn;
#pragma unroll
    for (int i = 0; i < 4; ++i) y[base + 16 * i] = acc[j][i] + bias;
  }
}

extern "C" void kernel_launch(void* const* d_in, const int* in_sizes, int n_in,
                              void* d_out, int out_size, void* d_ws, size_t ws_size,
                              hipStream_t stream) {
  const float* x   = (const float*)d_in[0];
  const float* wq  = (const float*)d_in[1];
  const float* wk  = (const float*)d_in[2];
  const float* wv  = (const float*)d_in[3];
  const float* wck = (const float*)d_in[4];
  const float* wcv = (const float*)d_in[5];
  const float* wo  = (const float*)d_in[6];
  const float* bo  = (const float*)d_in[7];
  float* out = (float*)d_out;

  float* ws = (float*)d_ws;
  const size_t SZ_FULL = (size_t)Bq * Cq * Nq;   // 8388608
  const size_t SZ_CMP  = (size_t)Bq * Cq * NCq;  // 524288
  float* q     = ws;
  float* kf    = q  + SZ_FULL;
  float* vf    = kf + SZ_FULL;
  float* ksc   = vf + SZ_FULL;
  float* vsc   = ksc + SZ_CMP;
  float* part  = vsc + SZ_CMP;                    // 64*8*256
  float* score = part + (size_t)BHq * 8 * NCq;    // 64*256
  int*   idx   = (int*)(score + (size_t)BHq * NCq);
  float* attn  = kf;  // reuse: kf dead after pooling

  qkv_proj<<<dim3(64, 4, 8), 256, 0, stream>>>(x, wq, wk, wv, q, kf, vf);
  pool_kv<<<dim3(Bq * Cq), 256, 0, stream>>>(kf, vf, wck, wcv, ksc, vsc);
  stage1_scores<<<dim3(8, BHq), 256, 0, stream>>>(q, ksc, part);
  reduce_scores<<<dim3(BHq), 256, 0, stream>>>(part, score);
  topk_sel<<<dim3(BHq), 256, 0, stream>>>(score, idx);
  stage2_attn<<<dim3(64, BHq), 256, 0, stream>>>(q, ksc, vsc, idx, attn);
  out_proj<<<dim3(64, 4, 8), 256, 0, stream>>>(attn, wo, bo, out);
}

// Round 2
// 456.525 us; speedup vs baseline: 1.1432x; 1.1432x over previous
//
#include <hip/hip_runtime.h>

#define Bq 8
#define Cq 256
#define Hq 64
#define Wq 64
#define Nq 4096        // H*W
#define HEADSq 8
#define DIMq 32
#define NCq 256        // compressed tokens 16*16
#define TOPKq 64
#define BHq 64
#define SCALEq 0.17677669529663687f   // 32^-0.5

// ---------------- K1: fused q/k/v 1x1 conv (3 GEMMs sharing x tiles) -------
// Per-thread tile: 4 consecutive o x 4 consecutive n per GEMM.
// LDS: xs[16][64] (linear writes), weights padded [16][68] -> <=2-way banks.
__global__ __launch_bounds__(256) void qkv_proj(
    const float* __restrict__ x,
    const float* __restrict__ wq, const float* __restrict__ wk, const float* __restrict__ wv,
    float* __restrict__ q, float* __restrict__ kf, float* __restrict__ vf) {
  const int b  = blockIdx.z;
  const int o0 = blockIdx.y * 64;
  const int n0 = blockIdx.x * 64;
  __shared__ float xs[16][64];
  __shared__ float wqs[16][68], wks[16][68], wvs[16][68];
  const int t = threadIdx.x;
  const int tn = t & 15;    // n group: n = n0 + tn*4 + i
  const int to = t >> 4;    // o group: o = o0 + to*4 + j
  float accq[4][4] = {}, acck[4][4] = {}, accv[4][4] = {};
  const float* xb = x + (size_t)b * Cq * Nq;
  // staging indices
  const int sx_c = t >> 4, sx_n = (t & 15) * 4;            // xs: row, col4
  const int sw_o = t >> 2, sw_c = (t & 3) * 4;             // weights: o, col4 of c

  for (int c0 = 0; c0 < Cq; c0 += 16) {
    __syncthreads();
    {  // xs stage: 16x64 floats, one float4 per thread, linear LDS write
      float4 v = *(const float4*)&xb[(size_t)(c0 + sx_c) * Nq + n0 + sx_n];
      *(float4*)&xs[sx_c][sx_n] = v;
    }
    {  // weight stage: 64 o x 16 c per array; float4 along c, scatter 4 rows
      float4 a = *(const float4*)&wq[(size_t)(o0 + sw_o) * Cq + c0 + sw_c];
      float4 bb = *(const float4*)&wk[(size_t)(o0 + sw_o) * Cq + c0 + sw_c];
      float4 c = *(const float4*)&wv[(size_t)(o0 + sw_o) * Cq + c0 + sw_c];
      wqs[sw_c + 0][sw_o] = a.x; wqs[sw_c + 1][sw_o] = a.y;
      wqs[sw_c + 2][sw_o] = a.z; wqs[sw_c + 3][sw_o] = a.w;
      wks[sw_c + 0][sw_o] = bb.x; wks[sw_c + 1][sw_o] = bb.y;
      wks[sw_c + 2][sw_o] = bb.z; wks[sw_c + 3][sw_o] = bb.w;
      wvs[sw_c + 0][sw_o] = c.x; wvs[sw_c + 1][sw_o] = c.y;
      wvs[sw_c + 2][sw_o] = c.z; wvs[sw_c + 3][sw_o] = c.w;
    }
    __syncthreads();
#pragma unroll
    for (int cc = 0; cc < 16; ++cc) {
      float4 xv = *(const float4*)&xs[cc][tn * 4];
      float4 wqv = *(const float4*)&wqs[cc][to * 4];
      float4 wkv = *(const float4*)&wks[cc][to * 4];
      float4 wvv = *(const float4*)&wvs[cc][to * 4];
      const float xa[4] = {xv.x, xv.y, xv.z, xv.w};
      const float qa[4] = {wqv.x, wqv.y, wqv.z, wqv.w};
      const float ka[4] = {wkv.x, wkv.y, wkv.z, wkv.w};
      const float va[4] = {wvv.x, wvv.y, wvv.z, wvv.w};
#pragma unroll
      for (int j = 0; j < 4; ++j)
#pragma unroll
        for (int i = 0; i < 4; ++i) {
          accq[j][i] += qa[j] * xa[i];
          acck[j][i] += ka[j] * xa[i];
          accv[j][i] += va[j] * xa[i];
        }
    }
  }
#pragma unroll
  for (int j = 0; j < 4; ++j) {
    int o = o0 + to * 4 + j;
    size_t base = ((size_t)b * Cq + o) * Nq + n0 + tn * 4;
    *(float4*)&q[base]  = make_float4(accq[j][0], accq[j][1], accq[j][2], accq[j][3]);
    *(float4*)&kf[base] = make_float4(acck[j][0], acck[j][1], acck[j][2], acck[j][3]);
    *(float4*)&vf[base] = make_float4(accv[j][0], accv[j][1], accv[j][2], accv[j][3]);
  }
}

// ---------------- K2: depthwise 4x4 non-overlapping pooling ---------------
__global__ __launch_bounds__(256) void pool_kv(
    const float* __restrict__ kf, const float* __restrict__ vf,
    const float* __restrict__ wck, const float* __restrict__ wcv,
    float* __restrict__ ks, float* __restrict__ vs) {
  int bc = blockIdx.x;
  int b = bc / Cq, c = bc % Cq;
  int t = threadIdx.x;
  int i = t >> 4, j = t & 15;
  const float* kp = kf + ((size_t)b * Cq + c) * Nq;
  const float* vp = vf + ((size_t)b * Cq + c) * Nq;
  __shared__ float wk_s[16], wv_s[16];
  if (t < 16) { wk_s[t] = wck[c * 16 + t]; wv_s[t] = wcv[c * 16 + t]; }
  __syncthreads();
  float ak = 0.f, av = 0.f;
#pragma unroll
  for (int r = 0; r < 4; ++r)
#pragma unroll
    for (int s = 0; s < 4; ++s) {
      int n = (i * 4 + r) * Wq + j * 4 + s;
      float wkv = wk_s[r * 4 + s], wvv = wv_s[r * 4 + s];
      ak += kp[n] * wkv;
      av += vp[n] * wvv;
    }
  ks[((size_t)b * Cq + c) * NCq + t] = ak;
  vs[((size_t)b * Cq + c) * NCq + t] = av;
}

// ---------------- K3a: stage-1 softmax column-sum (token scores) ----------
__global__ __launch_bounds__(256) void stage1_scores(
    const float* __restrict__ q, const float* __restrict__ ks,
    float* __restrict__ part) {
  const int bh = blockIdx.y;
  const int b = bh >> 3, h = bh & 7;
  const int row0 = blockIdx.x * 512;
  const int t = threadIdx.x;
  const int wave = t >> 6, lane = t & 63;
  __shared__ float kt[DIMq][NCq];       // 32 KB, [d][tok]
  __shared__ float qs[64][DIMq + 1];    // [row][d]
  __shared__ float sc[4][NCq];          // per-wave score accum

  const float* ksb = ks + ((size_t)b * Cq + h * DIMq) * NCq;
  for (int idx = t; idx < DIMq * NCq; idx += 256) {
    int d = idx >> 8, tok = idx & 255;
    kt[d][tok] = ksb[(size_t)d * NCq + tok];
  }
  for (int tok = t; tok < NCq; tok += 256) {
    sc[0][tok] = 0.f; sc[1][tok] = 0.f; sc[2][tok] = 0.f; sc[3][tok] = 0.f;
  }
  const float4* ktv = (const float4*)&kt[0][0];
  const float* qb = q + ((size_t)b * Cq + h * DIMq) * Nq;

  for (int ch = 0; ch < 8; ++ch) {
    int r0 = row0 + ch * 64;
    __syncthreads();
    for (int idx = t; idx < 64 * DIMq; idx += 256) {
      int d = idx >> 6, r = idx & 63;
      qs[r][d] = qb[(size_t)d * Nq + r0 + r];
    }
    __syncthreads();
    for (int rr = 0; rr < 16; rr += 4) {
      int r = wave * 16 + rr;
      float lg[4][4] = {};
#pragma unroll
      for (int d = 0; d < DIMq; ++d) {
        float4 kv = ktv[d * 64 + lane];
        float qv[4];
#pragma unroll
        for (int i = 0; i < 4; ++i) qv[i] = qs[r + i][d];
#pragma unroll
        for (int i = 0; i < 4; ++i) {
          lg[i][0] += qv[i] * kv.x;
          lg[i][1] += qv[i] * kv.y;
          lg[i][2] += qv[i] * kv.z;
          lg[i][3] += qv[i] * kv.w;
        }
      }
#pragma unroll
      for (int i = 0; i < 4; ++i) {
        float l0 = lg[i][0] * SCALEq, l1 = lg[i][1] * SCALEq;
        float l2 = lg[i][2] * SCALEq, l3 = lg[i][3] * SCALEq;
        float m = fmaxf(fmaxf(l0, l1), fmaxf(l2, l3));
        for (int off = 32; off; off >>= 1) m = fmaxf(m, __shfl_xor(m, off));
        float e0 = __expf(l0 - m), e1 = __expf(l1 - m);
        float e2 = __expf(l2 - m), e3 = __expf(l3 - m);
        float s = e0 + e1 + e2 + e3;
        for (int off = 32; off; off >>= 1) s += __shfl_xor(s, off);
        float inv = 1.0f / s;
        sc[wave][lane * 4 + 0] += e0 * inv;
        sc[wave][lane * 4 + 1] += e1 * inv;
        sc[wave][lane * 4 + 2] += e2 * inv;
        sc[wave][lane * 4 + 3] += e3 * inv;
      }
    }
  }
  __syncthreads();
  for (int tok = t; tok < NCq; tok += 256) {
    float v = sc[0][tok] + sc[1][tok] + sc[2][tok] + sc[3][tok];
    part[((size_t)bh * 8 + blockIdx.x) * NCq + tok] = v;
  }
}

// ---------------- K3b: reduce partial scores ------------------------------
__global__ __launch_bounds__(256) void reduce_scores(
    const float* __restrict__ part, float* __restrict__ score) {
  int bh = blockIdx.x, t = threadIdx.x;
  float s = 0.f;
#pragma unroll
  for (int c = 0; c < 8; ++c) s += part[((size_t)bh * 8 + c) * NCq + t];
  score[bh * NCq + t] = s;
}

// ---------------- K4: exact stable top-64 ---------------------------------
__global__ __launch_bounds__(256) void topk_sel(
    const float* __restrict__ score, int* __restrict__ idx) {
  int bh = blockIdx.x, t = threadIdx.x;
  __shared__ float s[NCq];
  s[t] = score[bh * NCq + t];
  __syncthreads();
  float st = s[t];
  int rank = 0;
  for (int j = 0; j < NCq; ++j) {
    float sj = s[j];
    rank += (sj > st) || (sj == st && j < t);
  }
  if (rank < TOPKq) idx[bh * TOPKq + rank] = t;
}

// ---------------- K5: stage-2 attention over selected tokens --------------
__global__ __launch_bounds__(256) void stage2_attn(
    const float* __restrict__ q, const float* __restrict__ ks,
    const float* __restrict__ vs, const int* __restrict__ idx,
    float* __restrict__ out) {
  const int bh = blockIdx.y, b = bh >> 3, h = bh & 7;
  const int n0 = blockIdx.x * 64;
  const int t = threadIdx.x;
  __shared__ float kt[DIMq][TOPKq];
  __shared__ float vt[DIMq][TOPKq];
  __shared__ float qs[DIMq][64];
  __shared__ float L[64][TOPKq + 1];
  const float* ksb = ks + ((size_t)b * Cq + h * DIMq) * NCq;
  const float* vsb = vs + ((size_t)b * Cq + h * DIMq) * NCq;
  const int* ib = idx + bh * TOPKq;
  for (int e = t; e < DIMq * TOPKq; e += 256) {
    int d = e >> 6, j = e & 63;
    int tok = ib[j];
    kt[d][j] = ksb[(size_t)d * NCq + tok];
    vt[d][j] = vsb[(size_t)d * NCq + tok];
  }
  const float* qb = q + ((size_t)b * Cq + h * DIMq) * Nq;
  for (int e = t; e < DIMq * 64; e += 256) {
    int d = e >> 6, r = e & 63;
    qs[d][r] = qb[(size_t)d * Nq + n0 + r];
  }
  __syncthreads();
  {  // phase A: logits [64 rows][64 toks]
    int r = t & 63;
    int tg = (t >> 6) * 16;
    float acc[16];
#pragma unroll
    for (int j = 0; j < 16; ++j) acc[j] = 0.f;
    for (int d = 0; d < DIMq; ++d) {
      float qd = qs[d][r];
#pragma unroll
      for (int j = 0; j < 16; ++j) acc[j] += qd * kt[d][tg + j];
    }
#pragma unroll
    for (int j = 0; j < 16; ++j) L[r][tg + j] = acc[j] * SCALEq;
  }
  __syncthreads();
  if (t < 64) {  // phase B: row softmax
    float m = -1e30f;
    for (int j = 0; j < TOPKq; ++j) m = fmaxf(m, L[t][j]);
    float s = 0.f;
    for (int j = 0; j < TOPKq; ++j) { float e = __expf(L[t][j] - m); L[t][j] = e; s += e; }
    float inv = 1.0f / s;
    for (int j = 0; j < TOPKq; ++j) L[t][j] *= inv;
  }
  __syncthreads();
  {  // phase C: out = attn @ v_top^T
    int r = t & 63;
    int d0 = (t >> 6) * 8;
    float acc[8] = {};
    for (int j = 0; j < TOPKq; ++j) {
      float a = L[r][j];
#pragma unroll
      for (int dd = 0; dd < 8; ++dd) acc[dd] += a * vt[d0 + dd][j];
    }
#pragma unroll
    for (int dd = 0; dd < 8; ++dd)
      out[((size_t)b * Cq + h * DIMq + d0 + dd) * Nq + n0 + r] = acc[dd];
  }
}

// ---------------- K6: output 1x1 conv + bias ------------------------------
// Per-thread tile: 8 consecutive o x 4 consecutive n. 128o x 64n per block.
__global__ __launch_bounds__(256) void out_proj(
    const float* __restrict__ a, const float* __restrict__ wo,
    const float* __restrict__ bo, float* __restrict__ y) {
  const int b = blockIdx.z, o0 = blockIdx.y * 128, n0 = blockIdx.x * 64;
  __shared__ float xs[16][64];
  __shared__ float wsp[16][132];
  const int t = threadIdx.x, tn = t & 15, to = t >> 4;
  float acc[8][4] = {};
  const float* ab = a + (size_t)b * Cq * Nq;
  const int sx_c = t >> 4, sx_n = (t & 15) * 4;
  const int sw_c = (t & 3) * 4;

  for (int c0 = 0; c0 < Cq; c0 += 16) {
    __syncthreads();
    {
      float4 v = *(const float4*)&ab[(size_t)(c0 + sx_c) * Nq + n0 + sx_n];
      *(float4*)&xs[sx_c][sx_n] = v;
    }
#pragma unroll
    for (int i = 0; i < 2; ++i) {  // 128 o x 16 c = 512 float4
      int o = (t + 256 * i) >> 2;
      float4 w = *(const float4*)&wo[(size_t)(o0 + o) * Cq + c0 + sw_c];
      wsp[sw_c + 0][o] = w.x; wsp[sw_c + 1][o] = w.y;
      wsp[sw_c + 2][o] = w.z; wsp[sw_c + 3][o] = w.w;
    }
    __syncthreads();
#pragma unroll
    for (int cc = 0; cc < 16; ++cc) {
      float4 xv = *(const float4*)&xs[cc][tn * 4];
      float4 w0 = *(const float4*)&wsp[cc][to * 8];
      float4 w1 = *(const float4*)&wsp[cc][to * 8 + 4];
      const float xa[4] = {xv.x, xv.y, xv.z, xv.w};
      const float wa[8] = {w0.x, w0.y, w0.z, w0.w, w1.x, w1.y, w1.z, w1.w};
#pragma unroll
      for (int j = 0; j < 8; ++j)
#pragma unroll
        for (int i = 0; i < 4; ++i) acc[j][i] += wa[j] * xa[i];
    }
  }
#pragma unroll
  for (int j = 0; j < 8; ++j) {
    int o = o0 + to * 8 + j;
    float bias = bo[o];
    size_t base = ((size_t)b * Cq + o) * Nq + n0 + tn * 4;
    *(float4*)&y[base] = make_float4(acc[j][0] + bias, acc[j][1] + bias,
                                     acc[j][2] + bias, acc[j][3] + bias);
  }
}

extern "C" void kernel_launch(void* const* d_in, const int* in_sizes, int n_in,
                              void* d_out, int out_size, void* d_ws, size_t ws_size,
                              hipStream_t stream) {
  const float* x   = (const float*)d_in[0];
  const float* wq  = (const float*)d_in[1];
  const float* wk  = (const float*)d_in[2];
  const float* wv  = (const float*)d_in[3];
  const float* wck = (const float*)d_in[4];
  const float* wcv = (const float*)d_in[5];
  const float* wo  = (const float*)d_in[6];
  const float* bo  = (const float*)d_in[7];
  float* out = (float*)d_out;

  float* ws = (float*)d_ws;
  const size_t SZ_FULL = (size_t)Bq * Cq * Nq;   // 8388608
  const size_t SZ_CMP  = (size_t)Bq * Cq * NCq;  // 524288
  float* q     = ws;
  float* kf    = q  + SZ_FULL;
  float* vf    = kf + SZ_FULL;
  float* ksc   = vf + SZ_FULL;
  float* vsc   = ksc + SZ_CMP;
  float* part  = vsc + SZ_CMP;
  float* score = part + (size_t)BHq * 8 * NCq;
  int*   idx   = (int*)(score + (size_t)BHq * NCq);
  float* attn  = kf;  // reuse: kf dead after pooling

  qkv_proj<<<dim3(64, 4, 8), 256, 0, stream>>>(x, wq, wk, wv, q, kf, vf);
  pool_kv<<<dim3(Bq * Cq), 256, 0, stream>>>(kf, vf, wck, wcv, ksc, vsc);
  stage1_scores<<<dim3(8, BHq), 256, 0, stream>>>(q, ksc, part);
  reduce_scores<<<dim3(BHq), 256, 0, stream>>>(part, score);
  topk_sel<<<dim3(BHq), 256, 0, stream>>>(score, idx);
  stage2_attn<<<dim3(64, BHq), 256, 0, stream>>>(q, ksc, vsc, idx, attn);
  out_proj<<<dim3(64, 2, 8), 256, 0, stream>>>(attn, wo, bo, out);
}

// Round 3
// 308.133 us; speedup vs baseline: 1.6938x; 1.4816x over previous
//
#include <hip/hip_runtime.h>

#define Bq 8
#define Cq 256
#define Hq 64
#define Wq 64
#define Nq 4096        // H*W
#define HEADSq 8
#define DIMq 32
#define NCq 256        // compressed tokens 16*16
#define TOPKq 64
#define BHq 64
#define SCALEq 0.17677669529663687f   // 32^-0.5

typedef short bf16x8 __attribute__((ext_vector_type(8)));
typedef float f32x16 __attribute__((ext_vector_type(16)));

// round-to-nearest-even bf16 (top 16 bits)
__device__ __forceinline__ uint32_t f2bf_hi(float f) {
  uint32_t u = __float_as_uint(f);
  return (u + 0x7FFFu + ((u >> 16) & 1u)) >> 16;
}

// split 8 floats into bf16 hi (RNE) + bf16 lo (residual, truncated), packed
__device__ __forceinline__ void split8(const float* v, uint4& hv, uint4& lv) {
  uint32_t h[8], l[8];
#pragma unroll
  for (int j = 0; j < 8; ++j) {
    uint32_t hb = f2bf_hi(v[j]);
    float rest = v[j] - __uint_as_float(hb << 16);
    h[j] = hb;
    l[j] = __float_as_uint(rest) >> 16;
  }
  hv = make_uint4(h[0] | (h[1] << 16), h[2] | (h[3] << 16),
                  h[4] | (h[5] << 16), h[6] | (h[7] << 16));
  lv = make_uint4(l[0] | (l[1] << 16), l[2] | (l[3] << 16),
                  l[4] | (l[5] << 16), l[6] | (l[7] << 16));
}

// Fragment-image layout for a 64(rows) x 32(k) bf16 tile (one K-step):
//   element (row, k): region = (row>>5)*2 + (k>>4)
//                     lane   = (row&31) + 32*((k&15)>>3)
//                     byte   = region*1024 + lane*16 + (k&7)*2
// A-frag / B-frag read for v_mfma_f32_32x32x16_bf16 is then base + lane*16
// (consecutive-lane 16B = conflict-free ds_read_b128).

// ---------------- P0: pre-split/swizzle the 4 weight matrices -------------
// wt layout: [mat(4)][oblk(4)][s(8)] -> 8192B image (hi 4KB | lo 4KB)
__global__ __launch_bounds__(256) void prep_w(
    const float* __restrict__ wq, const float* __restrict__ wk,
    const float* __restrict__ wv, const float* __restrict__ wo,
    char* __restrict__ wt) {
  const int oblk = blockIdx.x, s = blockIdx.y, mat = blockIdx.z;
  const float* w = mat == 0 ? wq : mat == 1 ? wk : mat == 2 ? wv : wo;
  const int t = threadIdx.x;
  const int o = t & 63, g = t >> 6;   // g: k-octet 0..3
  float v[8];
  const float* src = w + (size_t)(oblk * 64 + o) * Cq + s * 32 + g * 8;
#pragma unroll
  for (int j = 0; j < 8; ++j) v[j] = src[j];
  uint4 hv, lv;
  split8(v, hv, lv);
  size_t base = ((size_t)((mat * 4 + oblk) * 8 + s)) * 8192;
  int off = ((o >> 5) * 2 + (g >> 1)) * 1024 + ((o & 31) + 32 * (g & 1)) * 16;
  *(uint4*)(wt + base + off) = hv;
  *(uint4*)(wt + base + 4096 + off) = lv;
}

// ---------------- K1: fused q/k/v projection, bf16x3-split MFMA -----------
// block: 64o x 64n, 4 waves each 32x32; K-loop 8 steps of 32.
__global__ __launch_bounds__(256) void qkv_mfma(
    const float* __restrict__ x, const char* __restrict__ wt,
    float* __restrict__ q, float* __restrict__ kf, float* __restrict__ vf) {
  const int b = blockIdx.z, oblk = blockIdx.y, nblk = blockIdx.x;
  const int o0 = oblk * 64, n0 = nblk * 64;
  const int t = threadIdx.x, l = t & 63, wid = t >> 6;
  const int ob = wid >> 1, nbw = wid & 1;
  __shared__ __align__(16) short wimg[3][2][2048];  // 24KB
  __shared__ __align__(16) short ximg[2][2048];     // 8KB
  __shared__ __align__(16) float xf[32][64];        // 8KB
  f32x16 acc[3];
#pragma unroll
  for (int m = 0; m < 3; ++m)
#pragma unroll
    for (int i = 0; i < 16; ++i) acc[m][i] = 0.f;

  for (int s = 0; s < 8; ++s) {
    __syncthreads();
    // stage W images (3 x 8KB) linear copy
#pragma unroll
    for (int i = 0; i < 6; ++i) {
      const int m = i >> 1;
      const int off = t + (i & 1) * 256;
      ((uint4*)&wimg[m][0][0])[off] =
          ((const uint4*)(wt + ((size_t)((m * 4 + oblk) * 8 + s)) * 8192))[off];
    }
    // stage x fp32 tile 32c x 64n
    {
      const float* xb = x + ((size_t)(b * Cq + s * 32)) * Nq + n0;
#pragma unroll
      for (int i = 0; i < 2; ++i) {
        int e = t + i * 256;
        int cl = e >> 4, n4 = (e & 15) * 4;
        *(float4*)&xf[cl][n4] = *(const float4*)&xb[(size_t)cl * Nq + n4];
      }
    }
    __syncthreads();
    // transpose + bf16 split into fragment image
    {
      int n = t & 63, g = t >> 6;
      float v[8];
#pragma unroll
      for (int j = 0; j < 8; ++j) v[j] = xf[g * 8 + j][n];
      uint4 hv, lv;
      split8(v, hv, lv);
      int off = ((n >> 5) * 2 + (g >> 1)) * 1024 + ((n & 31) + 32 * (g & 1)) * 16;
      *(uint4*)((char*)&ximg[0][0] + off) = hv;
      *(uint4*)((char*)&ximg[1][0] + off) = lv;
    }
    __syncthreads();
    bf16x8 bh[2], bl[2];
#pragma unroll
    for (int kh = 0; kh < 2; ++kh) {
      int off = (nbw * 2 + kh) * 1024 + l * 16;
      bh[kh] = *(const bf16x8*)((const char*)&ximg[0][0] + off);
      bl[kh] = *(const bf16x8*)((const char*)&ximg[1][0] + off);
    }
#pragma unroll
    for (int m = 0; m < 3; ++m) {
#pragma unroll
      for (int kh = 0; kh < 2; ++kh) {
        int off = (ob * 2 + kh) * 1024 + l * 16;
        bf16x8 ah = *(const bf16x8*)((const char*)&wimg[m][0][0] + off);
        bf16x8 al = *(const bf16x8*)((const char*)&wimg[m][1][0] + off);
        acc[m] = __builtin_amdgcn_mfma_f32_32x32x16_bf16(ah, bh[kh], acc[m], 0, 0, 0);
        acc[m] = __builtin_amdgcn_mfma_f32_32x32x16_bf16(ah, bl[kh], acc[m], 0, 0, 0);
        acc[m] = __builtin_amdgcn_mfma_f32_32x32x16_bf16(al, bh[kh], acc[m], 0, 0, 0);
      }
    }
  }
  // store: D col = lane&31 (n), row = (r&3)+8*(r>>2)+4*(lane>>5) (o)
#pragma unroll
  for (int m = 0; m < 3; ++m) {
    float* dst = (m == 0 ? q : m == 1 ? kf : vf) + (size_t)b * Cq * Nq;
#pragma unroll
    for (int r = 0; r < 16; ++r) {
      int orow = o0 + ob * 32 + (r & 3) + 8 * (r >> 2) + 4 * (l >> 5);
      dst[(size_t)orow * Nq + n0 + nbw * 32 + (l & 31)] = acc[m][r];
    }
  }
}

// ---------------- K2: depthwise 4x4 non-overlapping pooling ---------------
__global__ __launch_bounds__(256) void pool_kv(
    const float* __restrict__ kf, const float* __restrict__ vf,
    const float* __restrict__ wck, const float* __restrict__ wcv,
    float* __restrict__ ks, float* __restrict__ vs) {
  int bc = blockIdx.x;
  int b = bc / Cq, c = bc % Cq;
  int t = threadIdx.x;
  int i = t >> 4, j = t & 15;
  const float* kp = kf + ((size_t)b * Cq + c) * Nq;
  const float* vp = vf + ((size_t)b * Cq + c) * Nq;
  __shared__ float wk_s[16], wv_s[16];
  if (t < 16) { wk_s[t] = wck[c * 16 + t]; wv_s[t] = wcv[c * 16 + t]; }
  __syncthreads();
  float ak = 0.f, av = 0.f;
#pragma unroll
  for (int r = 0; r < 4; ++r)
#pragma unroll
    for (int s = 0; s < 4; ++s) {
      int n = (i * 4 + r) * Wq + j * 4 + s;
      float wkv = wk_s[r * 4 + s], wvv = wv_s[r * 4 + s];
      ak += kp[n] * wkv;
      av += vp[n] * wvv;
    }
  ks[((size_t)b * Cq + c) * NCq + t] = ak;
  vs[((size_t)b * Cq + c) * NCq + t] = av;
}

// ---------------- K3a: stage-1 softmax column-sum (token scores) ----------
__global__ __launch_bounds__(256) void stage1_scores(
    const float* __restrict__ q, const float* __restrict__ ks,
    float* __restrict__ part) {
  const int bh = blockIdx.y;
  const int b = bh >> 3, h = bh & 7;
  const int row0 = blockIdx.x * 512;
  const int t = threadIdx.x;
  const int wave = t >> 6, lane = t & 63;
  __shared__ float kt[DIMq][NCq];
  __shared__ float qs[64][DIMq + 1];
  __shared__ float sc[4][NCq];

  const float* ksb = ks + ((size_t)b * Cq + h * DIMq) * NCq;
  for (int idx = t; idx < DIMq * NCq; idx += 256) {
    int d = idx >> 8, tok = idx & 255;
    kt[d][tok] = ksb[(size_t)d * NCq + tok];
  }
  for (int tok = t; tok < NCq; tok += 256) {
    sc[0][tok] = 0.f; sc[1][tok] = 0.f; sc[2][tok] = 0.f; sc[3][tok] = 0.f;
  }
  const float4* ktv = (const float4*)&kt[0][0];
  const float* qb = q + ((size_t)b * Cq + h * DIMq) * Nq;

  for (int ch = 0; ch < 8; ++ch) {
    int r0 = row0 + ch * 64;
    __syncthreads();
    for (int idx = t; idx < 64 * DIMq; idx += 256) {
      int d = idx >> 6, r = idx & 63;
      qs[r][d] = qb[(size_t)d * Nq + r0 + r];
    }
    __syncthreads();
    for (int rr = 0; rr < 16; rr += 4) {
      int r = wave * 16 + rr;
      float lg[4][4] = {};
#pragma unroll
      for (int d = 0; d < DIMq; ++d) {
        float4 kv = ktv[d * 64 + lane];
        float qv[4];
#pragma unroll
        for (int i = 0; i < 4; ++i) qv[i] = qs[r + i][d];
#pragma unroll
        for (int i = 0; i < 4; ++i) {
          lg[i][0] += qv[i] * kv.x;
          lg[i][1] += qv[i] * kv.y;
          lg[i][2] += qv[i] * kv.z;
          lg[i][3] += qv[i] * kv.w;
        }
      }
#pragma unroll
      for (int i = 0; i < 4; ++i) {
        float l0 = lg[i][0] * SCALEq, l1 = lg[i][1] * SCALEq;
        float l2 = lg[i][2] * SCALEq, l3 = lg[i][3] * SCALEq;
        float m = fmaxf(fmaxf(l0, l1), fmaxf(l2, l3));
        for (int off = 32; off; off >>= 1) m = fmaxf(m, __shfl_xor(m, off));
        float e0 = __expf(l0 - m), e1 = __expf(l1 - m);
        float e2 = __expf(l2 - m), e3 = __expf(l3 - m);
        float s = e0 + e1 + e2 + e3;
        for (int off = 32; off; off >>= 1) s += __shfl_xor(s, off);
        float inv = 1.0f / s;
        sc[wave][lane * 4 + 0] += e0 * inv;
        sc[wave][lane * 4 + 1] += e1 * inv;
        sc[wave][lane * 4 + 2] += e2 * inv;
        sc[wave][lane * 4 + 3] += e3 * inv;
      }
    }
  }
  __syncthreads();
  for (int tok = t; tok < NCq; tok += 256) {
    float v = sc[0][tok] + sc[1][tok] + sc[2][tok] + sc[3][tok];
    part[((size_t)bh * 8 + blockIdx.x) * NCq + tok] = v;
  }
}

// ---------------- K3b: reduce partial scores ------------------------------
__global__ __launch_bounds__(256) void reduce_scores(
    const float* __restrict__ part, float* __restrict__ score) {
  int bh = blockIdx.x, t = threadIdx.x;
  float s = 0.f;
#pragma unroll
  for (int c = 0; c < 8; ++c) s += part[((size_t)bh * 8 + c) * NCq + t];
  score[bh * NCq + t] = s;
}

// ---------------- K4: exact stable top-64 ---------------------------------
__global__ __launch_bounds__(256) void topk_sel(
    const float* __restrict__ score, int* __restrict__ idx) {
  int bh = blockIdx.x, t = threadIdx.x;
  __shared__ float s[NCq];
  s[t] = score[bh * NCq + t];
  __syncthreads();
  float st = s[t];
  int rank = 0;
  for (int j = 0; j < NCq; ++j) {
    float sj = s[j];
    rank += (sj > st) || (sj == st && j < t);
  }
  if (rank < TOPKq) idx[bh * TOPKq + rank] = t;
}

// ---------------- K5: stage-2 attention; writes bf16 hi/lo frag images ----
__global__ __launch_bounds__(256) void stage2_attn(
    const float* __restrict__ q, const float* __restrict__ ks,
    const float* __restrict__ vs, const int* __restrict__ idx,
    char* __restrict__ at) {
  const int bh = blockIdx.y, b = bh >> 3, h = bh & 7;
  const int nb = blockIdx.x;
  const int n0 = nb * 64;
  const int t = threadIdx.x;
  __shared__ float kt[DIMq][TOPKq];
  __shared__ float vt[DIMq][TOPKq];
  __shared__ float qs[DIMq][64];
  __shared__ float L[64][TOPKq + 1];
  const float* ksb = ks + ((size_t)b * Cq + h * DIMq) * NCq;
  const float* vsb = vs + ((size_t)b * Cq + h * DIMq) * NCq;
  const int* ib = idx + bh * TOPKq;
  for (int e = t; e < DIMq * TOPKq; e += 256) {
    int d = e >> 6, j = e & 63;
    int tok = ib[j];
    kt[d][j] = ksb[(size_t)d * NCq + tok];
    vt[d][j] = vsb[(size_t)d * NCq + tok];
  }
  const float* qb = q + ((size_t)b * Cq + h * DIMq) * Nq;
  for (int e = t; e < DIMq * 64; e += 256) {
    int d = e >> 6, r = e & 63;
    qs[d][r] = qb[(size_t)d * Nq + n0 + r];
  }
  __syncthreads();
  {  // phase A: logits
    int r = t & 63;
    int tg = (t >> 6) * 16;
    float acc[16];
#pragma unroll
    for (int j = 0; j < 16; ++j) acc[j] = 0.f;
    for (int d = 0; d < DIMq; ++d) {
      float qd = qs[d][r];
#pragma unroll
      for (int j = 0; j < 16; ++j) acc[j] += qd * kt[d][tg + j];
    }
#pragma unroll
    for (int j = 0; j < 16; ++j) L[r][tg + j] = acc[j] * SCALEq;
  }
  __syncthreads();
  if (t < 64) {  // phase B: row softmax
    float m = -1e30f;
    for (int j = 0; j < TOPKq; ++j) m = fmaxf(m, L[t][j]);
    float s = 0.f;
    for (int j = 0; j < TOPKq; ++j) { float e = __expf(L[t][j] - m); L[t][j] = e; s += e; }
    float inv = 1.0f / s;
    for (int j = 0; j < TOPKq; ++j) L[t][j] *= inv;
  }
  __syncthreads();
  {  // phase C: out = attn @ v_top^T -> bf16 hi/lo fragment image
    int r = t & 63;
    int d0 = (t >> 6) * 8;
    float acc[8] = {};
    for (int j = 0; j < TOPKq; ++j) {
      float a = L[r][j];
#pragma unroll
      for (int dd = 0; dd < 8; ++dd) acc[dd] += a * vt[d0 + dd][j];
    }
    uint4 hv, lv;
    split8(acc, hv, lv);
    size_t base = ((size_t)((b * 64 + nb) * 8 + h)) * 8192;  // K-step = head
    int off = ((r >> 5) * 2 + (d0 >> 4)) * 1024 +
              ((r & 31) + 32 * ((d0 >> 3) & 1)) * 16;
    *(uint4*)(at + base + off) = hv;
    *(uint4*)(at + base + 4096 + off) = lv;
  }
}

// ---------------- K6: output projection + bias, bf16x3-split MFMA ---------
__global__ __launch_bounds__(256) void out_mfma(
    const char* __restrict__ at, const char* __restrict__ wt,
    const float* __restrict__ bo, float* __restrict__ y) {
  const int b = blockIdx.z, oblk = blockIdx.y, nblk = blockIdx.x;
  const int o0 = oblk * 64, n0 = nblk * 64;
  const int t = threadIdx.x, l = t & 63, wid = t >> 6;
  const int ob = wid >> 1, nbw = wid & 1;
  __shared__ __align__(16) short wimg[2][2048];
  __shared__ __align__(16) short ximg[2][2048];
  __shared__ float bs[64];
  if (t < 64) bs[t] = bo[o0 + t];
  f32x16 acc;
#pragma unroll
  for (int i = 0; i < 16; ++i) acc[i] = 0.f;

  for (int s = 0; s < 8; ++s) {
    __syncthreads();
    {
      const uint4* srcw = (const uint4*)(wt + ((size_t)((12 + oblk) * 8 + s)) * 8192);
      const uint4* srcx = (const uint4*)(at + ((size_t)((b * 64 + nblk) * 8 + s)) * 8192);
#pragma unroll
      for (int i = 0; i < 2; ++i) {
        ((uint4*)&wimg[0][0])[t + i * 256] = srcw[t + i * 256];
        ((uint4*)&ximg[0][0])[t + i * 256] = srcx[t + i * 256];
      }
    }
    __syncthreads();
#pragma unroll
    for (int kh = 0; kh < 2; ++kh) {
      int offa = (ob * 2 + kh) * 1024 + l * 16;
      int offb = (nbw * 2 + kh) * 1024 + l * 16;
      bf16x8 ah = *(const bf16x8*)((const char*)&wimg[0][0] + offa);
      bf16x8 al = *(const bf16x8*)((const char*)&wimg[1][0] + offa);
      bf16x8 bh = *(const bf16x8*)((const char*)&ximg[0][0] + offb);
      bf16x8 bl = *(const bf16x8*)((const char*)&ximg[1][0] + offb);
      acc = __builtin_amdgcn_mfma_f32_32x32x16_bf16(ah, bh, acc, 0, 0, 0);
      acc = __builtin_amdgcn_mfma_f32_32x32x16_bf16(ah, bl, acc, 0, 0, 0);
      acc = __builtin_amdgcn_mfma_f32_32x32x16_bf16(al, bh, acc, 0, 0, 0);
    }
  }
#pragma unroll
  for (int r = 0; r < 16; ++r) {
    int ol = ob * 32 + (r & 3) + 8 * (r >> 2) + 4 * (l >> 5);
    y[((size_t)(b * Cq + o0 + ol)) * Nq + n0 + nbw * 32 + (l & 31)] = acc[r] + bs[ol];
  }
}

extern "C" void kernel_launch(void* const* d_in, const int* in_sizes, int n_in,
                              void* d_out, int out_size, void* d_ws, size_t ws_size,
                              hipStream_t stream) {
  const float* x   = (const float*)d_in[0];
  const float* wq  = (const float*)d_in[1];
  const float* wk  = (const float*)d_in[2];
  const float* wv  = (const float*)d_in[3];
  const float* wck = (const float*)d_in[4];
  const float* wcv = (const float*)d_in[5];
  const float* wo  = (const float*)d_in[6];
  const float* bo  = (const float*)d_in[7];
  float* out = (float*)d_out;

  float* ws = (float*)d_ws;
  const size_t SZ_FULL = (size_t)Bq * Cq * Nq;   // 8388608
  const size_t SZ_CMP  = (size_t)Bq * Cq * NCq;  // 524288
  float* q     = ws;
  float* kf    = q  + SZ_FULL;
  float* vf    = kf + SZ_FULL;
  float* ksc   = vf + SZ_FULL;
  float* vsc   = ksc + SZ_CMP;
  float* part  = vsc + SZ_CMP;
  float* score = part + (size_t)BHq * 8 * NCq;
  int*   idx   = (int*)(score + (size_t)BHq * NCq);
  char*  wt    = (char*)(idx + (size_t)BHq * TOPKq);  // 1MB weight images
  char*  at    = (char*)kf;  // reuse: kf dead after pool_kv

  prep_w<<<dim3(4, 8, 4), 256, 0, stream>>>(wq, wk, wv, wo, wt);
  qkv_mfma<<<dim3(64, 4, 8), 256, 0, stream>>>(x, wt, q, kf, vf);
  pool_kv<<<dim3(Bq * Cq), 256, 0, stream>>>(kf, vf, wck, wcv, ksc, vsc);
  stage1_scores<<<dim3(8, BHq), 256, 0, stream>>>(q, ksc, part);
  reduce_scores<<<dim3(BHq), 256, 0, stream>>>(part, score);
  topk_sel<<<dim3(BHq), 256, 0, stream>>>(score, idx);
  stage2_attn<<<dim3(64, BHq), 256, 0, stream>>>(q, ksc, vsc, idx, at);
  out_mfma<<<dim3(64, 4, 8), 256, 0, stream>>>(at, wt, bo, out);
}

// Round 4
// 216.252 us; speedup vs baseline: 2.4135x; 1.4249x over previous
//
#include <hip/hip_runtime.h>

#define Bq 8
#define Cq 256
#define Hq 64
#define Wq 64
#define Nq 4096        // H*W
#define HEADSq 8
#define DIMq 32
#define NCq 256        // compressed tokens 16*16
#define TOPKq 64
#define BHq 64
#define SCALEq 0.17677669529663687f   // 32^-0.5

typedef short bf16x8 __attribute__((ext_vector_type(8)));
typedef float f32x16 __attribute__((ext_vector_type(16)));

// round-to-nearest-even bf16 (top 16 bits)
__device__ __forceinline__ uint32_t f2bf_hi(float f) {
  uint32_t u = __float_as_uint(f);
  return (u + 0x7FFFu + ((u >> 16) & 1u)) >> 16;
}

// split 8 floats into bf16 hi (RNE) + bf16 lo (residual, truncated), packed
__device__ __forceinline__ void split8(const float* v, uint4& hv, uint4& lv) {
  uint32_t h[8], l[8];
#pragma unroll
  for (int j = 0; j < 8; ++j) {
    uint32_t hb = f2bf_hi(v[j]);
    float rest = v[j] - __uint_as_float(hb << 16);
    h[j] = hb;
    l[j] = __float_as_uint(rest) >> 16;
  }
  hv = make_uint4(h[0] | (h[1] << 16), h[2] | (h[3] << 16),
                  h[4] | (h[5] << 16), h[6] | (h[7] << 16));
  lv = make_uint4(l[0] | (l[1] << 16), l[2] | (l[3] << 16),
                  l[4] | (l[5] << 16), l[6] | (l[7] << 16));
}

// Fragment-image layout for a 64(rows) x 32(k) bf16 tile (one K-step):
//   element (row, k): region = (row>>5)*2 + (k>>4)
//                     lane   = (row&31) + 32*((k&15)>>3)
//                     byte   = region*1024 + lane*16 + (k&7)*2
// A/B-frag read for v_mfma_f32_32x32x16_bf16 is base + lane*16 (conflict-free).

// ---------------- P0: pre-split/swizzle the 4 weight matrices -------------
__global__ __launch_bounds__(256) void prep_w(
    const float* __restrict__ wq, const float* __restrict__ wk,
    const float* __restrict__ wv, const float* __restrict__ wo,
    char* __restrict__ wt) {
  const int oblk = blockIdx.x, s = blockIdx.y, mat = blockIdx.z;
  const float* w = mat == 0 ? wq : mat == 1 ? wk : mat == 2 ? wv : wo;
  const int t = threadIdx.x;
  const int o = t & 63, g = t >> 6;   // g: k-octet 0..3
  float v[8];
  const float* src = w + (size_t)(oblk * 64 + o) * Cq + s * 32 + g * 8;
#pragma unroll
  for (int j = 0; j < 8; ++j) v[j] = src[j];
  uint4 hv, lv;
  split8(v, hv, lv);
  size_t base = ((size_t)((mat * 4 + oblk) * 8 + s)) * 8192;
  int off = ((o >> 5) * 2 + (g >> 1)) * 1024 + ((o & 31) + 32 * (g & 1)) * 16;
  *(uint4*)(wt + base + off) = hv;
  *(uint4*)(wt + base + 4096 + off) = lv;
}

// ---------------- K1: fused q/k/v projection, bf16x3-split MFMA -----------
__global__ __launch_bounds__(256) void qkv_mfma(
    const float* __restrict__ x, const char* __restrict__ wt,
    float* __restrict__ q, float* __restrict__ kf, float* __restrict__ vf) {
  const int b = blockIdx.z, oblk = blockIdx.y, nblk = blockIdx.x;
  const int o0 = oblk * 64, n0 = nblk * 64;
  const int t = threadIdx.x, l = t & 63, wid = t >> 6;
  const int ob = wid >> 1, nbw = wid & 1;
  __shared__ __align__(16) short wimg[3][2][2048];  // 24KB
  __shared__ __align__(16) short ximg[2][2048];     // 8KB
  __shared__ __align__(16) float xf[32][64];        // 8KB
  f32x16 acc[3];
#pragma unroll
  for (int m = 0; m < 3; ++m)
#pragma unroll
    for (int i = 0; i < 16; ++i) acc[m][i] = 0.f;

  for (int s = 0; s < 8; ++s) {
    __syncthreads();
#pragma unroll
    for (int i = 0; i < 6; ++i) {
      const int m = i >> 1;
      const int off = t + (i & 1) * 256;
      ((uint4*)&wimg[m][0][0])[off] =
          ((const uint4*)(wt + ((size_t)((m * 4 + oblk) * 8 + s)) * 8192))[off];
    }
    {
      const float* xb = x + ((size_t)(b * Cq + s * 32)) * Nq + n0;
#pragma unroll
      for (int i = 0; i < 2; ++i) {
        int e = t + i * 256;
        int cl = e >> 4, n4 = (e & 15) * 4;
        *(float4*)&xf[cl][n4] = *(const float4*)&xb[(size_t)cl * Nq + n4];
      }
    }
    __syncthreads();
    {
      int n = t & 63, g = t >> 6;
      float v[8];
#pragma unroll
      for (int j = 0; j < 8; ++j) v[j] = xf[g * 8 + j][n];
      uint4 hv, lv;
      split8(v, hv, lv);
      int off = ((n >> 5) * 2 + (g >> 1)) * 1024 + ((n & 31) + 32 * (g & 1)) * 16;
      *(uint4*)((char*)&ximg[0][0] + off) = hv;
      *(uint4*)((char*)&ximg[1][0] + off) = lv;
    }
    __syncthreads();
    bf16x8 bh[2], bl[2];
#pragma unroll
    for (int kh = 0; kh < 2; ++kh) {
      int off = (nbw * 2 + kh) * 1024 + l * 16;
      bh[kh] = *(const bf16x8*)((const char*)&ximg[0][0] + off);
      bl[kh] = *(const bf16x8*)((const char*)&ximg[1][0] + off);
    }
#pragma unroll
    for (int m = 0; m < 3; ++m) {
#pragma unroll
      for (int kh = 0; kh < 2; ++kh) {
        int off = (ob * 2 + kh) * 1024 + l * 16;
        bf16x8 ah = *(const bf16x8*)((const char*)&wimg[m][0][0] + off);
        bf16x8 al = *(const bf16x8*)((const char*)&wimg[m][1][0] + off);
        acc[m] = __builtin_amdgcn_mfma_f32_32x32x16_bf16(ah, bh[kh], acc[m], 0, 0, 0);
        acc[m] = __builtin_amdgcn_mfma_f32_32x32x16_bf16(ah, bl[kh], acc[m], 0, 0, 0);
        acc[m] = __builtin_amdgcn_mfma_f32_32x32x16_bf16(al, bh[kh], acc[m], 0, 0, 0);
      }
    }
  }
#pragma unroll
  for (int m = 0; m < 3; ++m) {
    float* dst = (m == 0 ? q : m == 1 ? kf : vf) + (size_t)b * Cq * Nq;
#pragma unroll
    for (int r = 0; r < 16; ++r) {
      int orow = o0 + ob * 32 + (r & 3) + 8 * (r >> 2) + 4 * (l >> 5);
      dst[(size_t)orow * Nq + n0 + nbw * 32 + (l & 31)] = acc[m][r];
    }
  }
}

// ---------------- K2: depthwise 4x4 non-overlapping pooling ---------------
__global__ __launch_bounds__(256) void pool_kv(
    const float* __restrict__ kf, const float* __restrict__ vf,
    const float* __restrict__ wck, const float* __restrict__ wcv,
    float* __restrict__ ks, float* __restrict__ vs) {
  int bc = blockIdx.x;
  int b = bc / Cq, c = bc % Cq;
  int t = threadIdx.x;
  int i = t >> 4, j = t & 15;
  const float* kp = kf + ((size_t)b * Cq + c) * Nq;
  const float* vp = vf + ((size_t)b * Cq + c) * Nq;
  __shared__ float wk_s[16], wv_s[16];
  if (t < 16) { wk_s[t] = wck[c * 16 + t]; wv_s[t] = wcv[c * 16 + t]; }
  __syncthreads();
  float ak = 0.f, av = 0.f;
#pragma unroll
  for (int r = 0; r < 4; ++r)
#pragma unroll
    for (int s = 0; s < 4; ++s) {
      int n = (i * 4 + r) * Wq + j * 4 + s;
      float wkv = wk_s[r * 4 + s], wvv = wv_s[r * 4 + s];
      ak += kp[n] * wkv;
      av += vp[n] * wvv;
    }
  ks[((size_t)b * Cq + c) * NCq + t] = ak;
  vs[((size_t)b * Cq + c) * NCq + t] = av;
}

// ---------------- K3a: stage-1 scores via MFMA + in-register softmax ------
// grid (8, 64). Block: 512 qrows (4 steps x 128); wave handles 32 qrows/step.
// D = mfma(Q, K): reg r,lane l -> qrow=(r&3)+8*(r>>2)+4*(l>>5), token=g*32+(l&31).
__global__ __launch_bounds__(256, 2) void stage1_mfma(
    const float* __restrict__ q, const float* __restrict__ ks,
    float* __restrict__ part) {
  const int bh = blockIdx.y, b = bh >> 3, h = bh & 7;
  const int row0 = blockIdx.x * 512;
  const int t = threadIdx.x, l = t & 63, wid = t >> 6;
  __shared__ __align__(16) short kimg[2][4][2048];   // 32KB [hi/lo][img][]
  __shared__ __align__(16) short qimg[2][2][2048];   // 16KB
  __shared__ __align__(16) float xf[32][128];        // 16KB
  __shared__ float sc[4][256];                       // 4KB

  const float* qb = q + ((size_t)b * Cq + h * DIMq) * Nq;
  const float* kb = ks + ((size_t)b * Cq + h * DIMq) * NCq;

  // ---- stage K into fragment images (2 halves of 128 tokens), once ----
#pragma unroll
  for (int half = 0; half < 2; ++half) {
    __syncthreads();
#pragma unroll
    for (int i = 0; i < 4; ++i) {
      int row = (t >> 5) + i * 8, c4 = (t & 31) * 4;
      *(float4*)&xf[row][c4] =
          *(const float4*)&kb[(size_t)row * NCq + half * 128 + c4];
    }
    __syncthreads();
#pragma unroll
    for (int i = 0; i < 2; ++i) {
      int e = t + i * 256;
      int n = e & 127, g = e >> 7;
      float v[8];
#pragma unroll
      for (int j = 0; j < 8; ++j) v[j] = xf[g * 8 + j][n];
      uint4 hv, lv;
      split8(v, hv, lv);
      int img = half * 2 + (n >> 6), row = n & 63;
      int off = ((row >> 5) * 2 + (g >> 1)) * 1024 +
                ((row & 31) + 32 * (g & 1)) * 16;
      *(uint4*)((char*)&kimg[0][img][0] + off) = hv;
      *(uint4*)((char*)&kimg[1][img][0] + off) = lv;
    }
  }

  float scoreacc[8];
#pragma unroll
  for (int g = 0; g < 8; ++g) scoreacc[g] = 0.f;

  for (int step = 0; step < 4; ++step) {
    const int r0 = row0 + step * 128;
    __syncthreads();
#pragma unroll
    for (int i = 0; i < 4; ++i) {
      int row = (t >> 5) + i * 8, c4 = (t & 31) * 4;
      *(float4*)&xf[row][c4] = *(const float4*)&qb[(size_t)row * Nq + r0 + c4];
    }
    __syncthreads();
#pragma unroll
    for (int i = 0; i < 2; ++i) {
      int e = t + i * 256;
      int n = e & 127, g = e >> 7;
      float v[8];
#pragma unroll
      for (int j = 0; j < 8; ++j) v[j] = xf[g * 8 + j][n];
      uint4 hv, lv;
      split8(v, hv, lv);
      int img = n >> 6, row = n & 63;
      int off = ((row >> 5) * 2 + (g >> 1)) * 1024 +
                ((row & 31) + 32 * (g & 1)) * 16;
      *(uint4*)((char*)&qimg[0][img][0] + off) = hv;
      *(uint4*)((char*)&qimg[1][img][0] + off) = lv;
    }
    __syncthreads();
    bf16x8 ah[2], al[2];
#pragma unroll
    for (int kh = 0; kh < 2; ++kh) {
      int off = ((wid & 1) * 2 + kh) * 1024 + l * 16;
      ah[kh] = *(const bf16x8*)((const char*)&qimg[0][wid >> 1][0] + off);
      al[kh] = *(const bf16x8*)((const char*)&qimg[1][wid >> 1][0] + off);
    }
    f32x16 acc[8];
#pragma unroll
    for (int g = 0; g < 8; ++g)
#pragma unroll
      for (int r = 0; r < 16; ++r) acc[g][r] = 0.f;
#pragma unroll
    for (int img = 0; img < 4; ++img)
#pragma unroll
      for (int nb = 0; nb < 2; ++nb) {
        const int g = img * 2 + nb;
#pragma unroll
        for (int kh = 0; kh < 2; ++kh) {
          int off = (nb * 2 + kh) * 1024 + l * 16;
          bf16x8 bh = *(const bf16x8*)((const char*)&kimg[0][img][0] + off);
          bf16x8 bl = *(const bf16x8*)((const char*)&kimg[1][img][0] + off);
          acc[g] = __builtin_amdgcn_mfma_f32_32x32x16_bf16(ah[kh], bh, acc[g], 0, 0, 0);
          acc[g] = __builtin_amdgcn_mfma_f32_32x32x16_bf16(ah[kh], bl, acc[g], 0, 0, 0);
          acc[g] = __builtin_amdgcn_mfma_f32_32x32x16_bf16(al[kh], bh, acc[g], 0, 0, 0);
        }
      }
    // in-register softmax over tokens: 8 regs (g) x 32 lanes (l&31)
    float mx[16], sm[16];
#pragma unroll
    for (int r = 0; r < 16; ++r) {
      float m = acc[0][r];
#pragma unroll
      for (int g = 1; g < 8; ++g) m = fmaxf(m, acc[g][r]);
      mx[r] = m;
    }
#pragma unroll
    for (int off = 1; off < 32; off <<= 1)
#pragma unroll
      for (int r = 0; r < 16; ++r) mx[r] = fmaxf(mx[r], __shfl_xor(mx[r], off));
#pragma unroll
    for (int r = 0; r < 16; ++r) sm[r] = 0.f;
#pragma unroll
    for (int g = 0; g < 8; ++g)
#pragma unroll
      for (int r = 0; r < 16; ++r) {
        float e = __expf((acc[g][r] - mx[r]) * SCALEq);
        acc[g][r] = e;
        sm[r] += e;
      }
#pragma unroll
    for (int off = 1; off < 32; off <<= 1)
#pragma unroll
      for (int r = 0; r < 16; ++r) sm[r] += __shfl_xor(sm[r], off);
#pragma unroll
    for (int r = 0; r < 16; ++r) sm[r] = 1.0f / sm[r];
#pragma unroll
    for (int g = 0; g < 8; ++g) {
      float tp = 0.f;
#pragma unroll
      for (int r = 0; r < 16; ++r) tp += acc[g][r] * sm[r];
      tp += __shfl_xor(tp, 32);
      scoreacc[g] += tp;
    }
  }
  if (l < 32) {
#pragma unroll
    for (int g = 0; g < 8; ++g) sc[wid][g * 32 + l] = scoreacc[g];
  }
  __syncthreads();
  {
    float v = sc[0][t] + sc[1][t] + sc[2][t] + sc[3][t];
    part[((size_t)bh * 8 + blockIdx.x) * NCq + t] = v;
  }
}

// ---------------- K3b: reduce partial scores ------------------------------
__global__ __launch_bounds__(256) void reduce_scores(
    const float* __restrict__ part, float* __restrict__ score) {
  int bh = blockIdx.x, t = threadIdx.x;
  float s = 0.f;
#pragma unroll
  for (int c = 0; c < 8; ++c) s += part[((size_t)bh * 8 + c) * NCq + t];
  score[bh * NCq + t] = s;
}

// ---------------- K4: exact stable top-64 ---------------------------------
__global__ __launch_bounds__(256) void topk_sel(
    const float* __restrict__ score, int* __restrict__ idx) {
  int bh = blockIdx.x, t = threadIdx.x;
  __shared__ float s[NCq];
  s[t] = score[bh * NCq + t];
  __syncthreads();
  float st = s[t];
  int rank = 0;
  for (int j = 0; j < NCq; ++j) {
    float sj = s[j];
    rank += (sj > st) || (sj == st && j < t);
  }
  if (rank < TOPKq) idx[bh * TOPKq + rank] = t;
}

// ---------------- K5: stage-2 attention; writes bf16 hi/lo frag images ----
__global__ __launch_bounds__(256) void stage2_attn(
    const float* __restrict__ q, const float* __restrict__ ks,
    const float* __restrict__ vs, const int* __restrict__ idx,
    char* __restrict__ at) {
  const int bh = blockIdx.y, b = bh >> 3, h = bh & 7;
  const int nb = blockIdx.x;
  const int n0 = nb * 64;
  const int t = threadIdx.x;
  __shared__ float kt[DIMq][TOPKq];
  __shared__ float vt[DIMq][TOPKq];
  __shared__ float qs[DIMq][64];
  __shared__ float L[64][TOPKq + 1];
  const float* ksb = ks + ((size_t)b * Cq + h * DIMq) * NCq;
  const float* vsb = vs + ((size_t)b * Cq + h * DIMq) * NCq;
  const int* ib = idx + bh * TOPKq;
  for (int e = t; e < DIMq * TOPKq; e += 256) {
    int d = e >> 6, j = e & 63;
    int tok = ib[j];
    kt[d][j] = ksb[(size_t)d * NCq + tok];
    vt[d][j] = vsb[(size_t)d * NCq + tok];
  }
  const float* qb = q + ((size_t)b * Cq + h * DIMq) * Nq;
  for (int e = t; e < DIMq * 64; e += 256) {
    int d = e >> 6, r = e & 63;
    qs[d][r] = qb[(size_t)d * Nq + n0 + r];
  }
  __syncthreads();
  {  // phase A: logits
    int r = t & 63;
    int tg = (t >> 6) * 16;
    float acc[16];
#pragma unroll
    for (int j = 0; j < 16; ++j) acc[j] = 0.f;
    for (int d = 0; d < DIMq; ++d) {
      float qd = qs[d][r];
#pragma unroll
      for (int j = 0; j < 16; ++j) acc[j] += qd * kt[d][tg + j];
    }
#pragma unroll
    for (int j = 0; j < 16; ++j) L[r][tg + j] = acc[j] * SCALEq;
  }
  __syncthreads();
  if (t < 64) {  // phase B: row softmax
    float m = -1e30f;
    for (int j = 0; j < TOPKq; ++j) m = fmaxf(m, L[t][j]);
    float s = 0.f;
    for (int j = 0; j < TOPKq; ++j) { float e = __expf(L[t][j] - m); L[t][j] = e; s += e; }
    float inv = 1.0f / s;
    for (int j = 0; j < TOPKq; ++j) L[t][j] *= inv;
  }
  __syncthreads();
  {  // phase C: out = attn @ v_top^T -> bf16 hi/lo fragment image
    int r = t & 63;
    int d0 = (t >> 6) * 8;
    float acc[8] = {};
    for (int j = 0; j < TOPKq; ++j) {
      float a = L[r][j];
#pragma unroll
      for (int dd = 0; dd < 8; ++dd) acc[dd] += a * vt[d0 + dd][j];
    }
    uint4 hv, lv;
    split8(acc, hv, lv);
    size_t base = ((size_t)((b * 64 + nb) * 8 + h)) * 8192;  // K-step = head
    int off = ((r >> 5) * 2 + (d0 >> 4)) * 1024 +
              ((r & 31) + 32 * ((d0 >> 3) & 1)) * 16;
    *(uint4*)(at + base + off) = hv;
    *(uint4*)(at + base + 4096 + off) = lv;
  }
}

// ---------------- K6: output projection + bias, bf16x3-split MFMA ---------
__global__ __launch_bounds__(256) void out_mfma(
    const char* __restrict__ at, const char* __restrict__ wt,
    const float* __restrict__ bo, float* __restrict__ y) {
  const int b = blockIdx.z, oblk = blockIdx.y, nblk = blockIdx.x;
  const int o0 = oblk * 64, n0 = nblk * 64;
  const int t = threadIdx.x, l = t & 63, wid = t >> 6;
  const int ob = wid >> 1, nbw = wid & 1;
  __shared__ __align__(16) short wimg[2][2048];
  __shared__ __align__(16) short ximg[2][2048];
  __shared__ float bs[64];
  if (t < 64) bs[t] = bo[o0 + t];
  f32x16 acc;
#pragma unroll
  for (int i = 0; i < 16; ++i) acc[i] = 0.f;

  for (int s = 0; s < 8; ++s) {
    __syncthreads();
    {
      const uint4* srcw = (const uint4*)(wt + ((size_t)((12 + oblk) * 8 + s)) * 8192);
      const uint4* srcx = (const uint4*)(at + ((size_t)((b * 64 + nblk) * 8 + s)) * 8192);
#pragma unroll
      for (int i = 0; i < 2; ++i) {
        ((uint4*)&wimg[0][0])[t + i * 256] = srcw[t + i * 256];
        ((uint4*)&ximg[0][0])[t + i * 256] = srcx[t + i * 256];
      }
    }
    __syncthreads();
#pragma unroll
    for (int kh = 0; kh < 2; ++kh) {
      int offa = (ob * 2 + kh) * 1024 + l * 16;
      int offb = (nbw * 2 + kh) * 1024 + l * 16;
      bf16x8 ah = *(const bf16x8*)((const char*)&wimg[0][0] + offa);
      bf16x8 al = *(const bf16x8*)((const char*)&wimg[1][0] + offa);
      bf16x8 bh = *(const bf16x8*)((const char*)&ximg[0][0] + offb);
      bf16x8 bl = *(const bf16x8*)((const char*)&ximg[1][0] + offb);
      acc = __builtin_amdgcn_mfma_f32_32x32x16_bf16(ah, bh, acc, 0, 0, 0);
      acc = __builtin_amdgcn_mfma_f32_32x32x16_bf16(ah, bl, acc, 0, 0, 0);
      acc = __builtin_amdgcn_mfma_f32_32x32x16_bf16(al, bh, acc, 0, 0, 0);
    }
  }
#pragma unroll
  for (int r = 0; r < 16; ++r) {
    int ol = ob * 32 + (r & 3) + 8 * (r >> 2) + 4 * (l >> 5);
    y[((size_t)(b * Cq + o0 + ol)) * Nq + n0 + nbw * 32 + (l & 31)] = acc[r] + bs[ol];
  }
}

extern "C" void kernel_launch(void* const* d_in, const int* in_sizes, int n_in,
                              void* d_out, int out_size, void* d_ws, size_t ws_size,
                              hipStream_t stream) {
  const float* x   = (const float*)d_in[0];
  const float* wq  = (const float*)d_in[1];
  const float* wk  = (const float*)d_in[2];
  const float* wv  = (const float*)d_in[3];
  const float* wck = (const float*)d_in[4];
  const float* wcv = (const float*)d_in[5];
  const float* wo  = (const float*)d_in[6];
  const float* bo  = (const float*)d_in[7];
  float* out = (float*)d_out;

  float* ws = (float*)d_ws;
  const size_t SZ_FULL = (size_t)Bq * Cq * Nq;   // 8388608
  const size_t SZ_CMP  = (size_t)Bq * Cq * NCq;  // 524288
  float* q     = ws;
  float* kf    = q  + SZ_FULL;
  float* vf    = kf + SZ_FULL;
  float* ksc   = vf + SZ_FULL;
  float* vsc   = ksc + SZ_CMP;
  float* part  = vsc + SZ_CMP;
  float* score = part + (size_t)BHq * 8 * NCq;
  int*   idx   = (int*)(score + (size_t)BHq * NCq);
  char*  wt    = (char*)(idx + (size_t)BHq * TOPKq);  // 1MB weight images
  char*  at    = (char*)kf;  // reuse: kf dead after pool_kv

  prep_w<<<dim3(4, 8, 4), 256, 0, stream>>>(wq, wk, wv, wo, wt);
  qkv_mfma<<<dim3(64, 4, 8), 256, 0, stream>>>(x, wt, q, kf, vf);
  pool_kv<<<dim3(Bq * Cq), 256, 0, stream>>>(kf, vf, wck, wcv, ksc, vsc);
  stage1_mfma<<<dim3(8, BHq), 256, 0, stream>>>(q, ksc, part);
  reduce_scores<<<dim3(BHq), 256, 0, stream>>>(part, score);
  topk_sel<<<dim3(BHq), 256, 0, stream>>>(score, idx);
  stage2_attn<<<dim3(64, BHq), 256, 0, stream>>>(q, ksc, vsc, idx, at);
  out_mfma<<<dim3(64, 4, 8), 256, 0, stream>>>(at, wt, bo, out);
}

// Round 5
// 185.286 us; speedup vs baseline: 2.8168x; 1.1671x over previous
//
#include <hip/hip_runtime.h>

#define Bq 8
#define Cq 256
#define Hq 64
#define Wq 64
#define Nq 4096        // H*W
#define HEADSq 8
#define DIMq 32
#define NCq 256        // compressed tokens 16*16
#define TOPKq 64
#define BHq 64
#define SCALEq 0.17677669529663687f   // 32^-0.5

typedef short bf16x8 __attribute__((ext_vector_type(8)));
typedef float f32x16 __attribute__((ext_vector_type(16)));

// round-to-nearest-even bf16 (top 16 bits)
__device__ __forceinline__ uint32_t f2bf_hi(float f) {
  uint32_t u = __float_as_uint(f);
  return (u + 0x7FFFu + ((u >> 16) & 1u)) >> 16;
}

// split 8 floats into bf16 hi (RNE) + bf16 lo (residual, truncated), packed
__device__ __forceinline__ void split8(const float* v, uint4& hv, uint4& lv) {
  uint32_t h[8], l[8];
#pragma unroll
  for (int j = 0; j < 8; ++j) {
    uint32_t hb = f2bf_hi(v[j]);
    float rest = v[j] - __uint_as_float(hb << 16);
    h[j] = hb;
    l[j] = __float_as_uint(rest) >> 16;
  }
  hv = make_uint4(h[0] | (h[1] << 16), h[2] | (h[3] << 16),
                  h[4] | (h[5] << 16), h[6] | (h[7] << 16));
  lv = make_uint4(l[0] | (l[1] << 16), l[2] | (l[3] << 16),
                  l[4] | (l[5] << 16), l[6] | (l[7] << 16));
}

// Fragment-image layout for a 64(rows) x 32(k) bf16 tile (one K-step):
//   element (row, k): region = (row>>5)*2 + (k>>4)
//                     lane   = (row&31) + 32*((k&15)>>3)
//                     byte   = region*1024 + lane*16 + (k&7)*2
// A/B-frag read for v_mfma_f32_32x32x16_bf16 is base + lane*16 (conflict-free).

// ---------------- P0: pre-split/swizzle the 4 weight matrices -------------
__global__ __launch_bounds__(256) void prep_w(
    const float* __restrict__ wq, const float* __restrict__ wk,
    const float* __restrict__ wv, const float* __restrict__ wo,
    char* __restrict__ wt) {
  const int oblk = blockIdx.x, s = blockIdx.y, mat = blockIdx.z;
  const float* w = mat == 0 ? wq : mat == 1 ? wk : mat == 2 ? wv : wo;
  const int t = threadIdx.x;
  const int o = t & 63, g = t >> 6;   // g: k-octet 0..3
  float v[8];
  const float* src = w + (size_t)(oblk * 64 + o) * Cq + s * 32 + g * 8;
#pragma unroll
  for (int j = 0; j < 8; ++j) v[j] = src[j];
  uint4 hv, lv;
  split8(v, hv, lv);
  size_t base = ((size_t)((mat * 4 + oblk) * 8 + s)) * 8192;
  int off = ((o >> 5) * 2 + (g >> 1)) * 1024 + ((o & 31) + 32 * (g & 1)) * 16;
  *(uint4*)(wt + base + off) = hv;
  *(uint4*)(wt + base + 4096 + off) = lv;
}

// ---------------- K1: fused q/k/v projection, bf16x3-split MFMA -----------
__global__ __launch_bounds__(256) void qkv_mfma(
    const float* __restrict__ x, const char* __restrict__ wt,
    float* __restrict__ q, float* __restrict__ kf, float* __restrict__ vf) {
  const int b = blockIdx.z, oblk = blockIdx.y, nblk = blockIdx.x;
  const int o0 = oblk * 64, n0 = nblk * 64;
  const int t = threadIdx.x, l = t & 63, wid = t >> 6;
  const int ob = wid >> 1, nbw = wid & 1;
  __shared__ __align__(16) short wimg[3][2][2048];  // 24KB
  __shared__ __align__(16) short ximg[2][2048];     // 8KB
  __shared__ __align__(16) float xf[32][64];        // 8KB
  f32x16 acc[3];
#pragma unroll
  for (int m = 0; m < 3; ++m)
#pragma unroll
    for (int i = 0; i < 16; ++i) acc[m][i] = 0.f;

  for (int s = 0; s < 8; ++s) {
    __syncthreads();
#pragma unroll
    for (int i = 0; i < 6; ++i) {
      const int m = i >> 1;
      const int off = t + (i & 1) * 256;
      ((uint4*)&wimg[m][0][0])[off] =
          ((const uint4*)(wt + ((size_t)((m * 4 + oblk) * 8 + s)) * 8192))[off];
    }
    {
      const float* xb = x + ((size_t)(b * Cq + s * 32)) * Nq + n0;
#pragma unroll
      for (int i = 0; i < 2; ++i) {
        int e = t + i * 256;
        int cl = e >> 4, n4 = (e & 15) * 4;
        *(float4*)&xf[cl][n4] = *(const float4*)&xb[(size_t)cl * Nq + n4];
      }
    }
    __syncthreads();
    {
      int n = t & 63, g = t >> 6;
      float v[8];
#pragma unroll
      for (int j = 0; j < 8; ++j) v[j] = xf[g * 8 + j][n];
      uint4 hv, lv;
      split8(v, hv, lv);
      int off = ((n >> 5) * 2 + (g >> 1)) * 1024 + ((n & 31) + 32 * (g & 1)) * 16;
      *(uint4*)((char*)&ximg[0][0] + off) = hv;
      *(uint4*)((char*)&ximg[1][0] + off) = lv;
    }
    __syncthreads();
    bf16x8 bh[2], bl[2];
#pragma unroll
    for (int kh = 0; kh < 2; ++kh) {
      int off = (nbw * 2 + kh) * 1024 + l * 16;
      bh[kh] = *(const bf16x8*)((const char*)&ximg[0][0] + off);
      bl[kh] = *(const bf16x8*)((const char*)&ximg[1][0] + off);
    }
#pragma unroll
    for (int m = 0; m < 3; ++m) {
#pragma unroll
      for (int kh = 0; kh < 2; ++kh) {
        int off = (ob * 2 + kh) * 1024 + l * 16;
        bf16x8 ah = *(const bf16x8*)((const char*)&wimg[m][0][0] + off);
        bf16x8 al = *(const bf16x8*)((const char*)&wimg[m][1][0] + off);
        acc[m] = __builtin_amdgcn_mfma_f32_32x32x16_bf16(ah, bh[kh], acc[m], 0, 0, 0);
        acc[m] = __builtin_amdgcn_mfma_f32_32x32x16_bf16(ah, bl[kh], acc[m], 0, 0, 0);
        acc[m] = __builtin_amdgcn_mfma_f32_32x32x16_bf16(al, bh[kh], acc[m], 0, 0, 0);
      }
    }
  }
#pragma unroll
  for (int m = 0; m < 3; ++m) {
    float* dst = (m == 0 ? q : m == 1 ? kf : vf) + (size_t)b * Cq * Nq;
#pragma unroll
    for (int r = 0; r < 16; ++r) {
      int orow = o0 + ob * 32 + (r & 3) + 8 * (r >> 2) + 4 * (l >> 5);
      dst[(size_t)orow * Nq + n0 + nbw * 32 + (l & 31)] = acc[m][r];
    }
  }
}

// ---------------- K2: depthwise 4x4 non-overlapping pooling ---------------
__global__ __launch_bounds__(256) void pool_kv(
    const float* __restrict__ kf, const float* __restrict__ vf,
    const float* __restrict__ wck, const float* __restrict__ wcv,
    float* __restrict__ ks, float* __restrict__ vs) {
  int bc = blockIdx.x;
  int b = bc / Cq, c = bc % Cq;
  int t = threadIdx.x;
  int i = t >> 4, j = t & 15;
  const float* kp = kf + ((size_t)b * Cq + c) * Nq;
  const float* vp = vf + ((size_t)b * Cq + c) * Nq;
  __shared__ float wk_s[16], wv_s[16];
  if (t < 16) { wk_s[t] = wck[c * 16 + t]; wv_s[t] = wcv[c * 16 + t]; }
  __syncthreads();
  float ak = 0.f, av = 0.f;
#pragma unroll
  for (int r = 0; r < 4; ++r)
#pragma unroll
    for (int s = 0; s < 4; ++s) {
      int n = (i * 4 + r) * Wq + j * 4 + s;
      float wkv = wk_s[r * 4 + s], wvv = wv_s[r * 4 + s];
      ak += kp[n] * wkv;
      av += vp[n] * wvv;
    }
  ks[((size_t)b * Cq + c) * NCq + t] = ak;
  vs[((size_t)b * Cq + c) * NCq + t] = av;
}

// ---------------- K3a: stage-1 scores via MFMA + in-register softmax ------
__global__ __launch_bounds__(256, 2) void stage1_mfma(
    const float* __restrict__ q, const float* __restrict__ ks,
    float* __restrict__ part) {
  const int bh = blockIdx.y, b = bh >> 3, h = bh & 7;
  const int row0 = blockIdx.x * 512;
  const int t = threadIdx.x, l = t & 63, wid = t >> 6;
  __shared__ __align__(16) short kimg[2][4][2048];   // 32KB [hi/lo][img][]
  __shared__ __align__(16) short qimg[2][2][2048];   // 16KB
  __shared__ __align__(16) float xf[32][128];        // 16KB
  __shared__ float sc[4][256];                       // 4KB

  const float* qb = q + ((size_t)b * Cq + h * DIMq) * Nq;
  const float* kb = ks + ((size_t)b * Cq + h * DIMq) * NCq;

#pragma unroll
  for (int half = 0; half < 2; ++half) {
    __syncthreads();
#pragma unroll
    for (int i = 0; i < 4; ++i) {
      int row = (t >> 5) + i * 8, c4 = (t & 31) * 4;
      *(float4*)&xf[row][c4] =
          *(const float4*)&kb[(size_t)row * NCq + half * 128 + c4];
    }
    __syncthreads();
#pragma unroll
    for (int i = 0; i < 2; ++i) {
      int e = t + i * 256;
      int n = e & 127, g = e >> 7;
      float v[8];
#pragma unroll
      for (int j = 0; j < 8; ++j) v[j] = xf[g * 8 + j][n];
      uint4 hv, lv;
      split8(v, hv, lv);
      int img = half * 2 + (n >> 6), row = n & 63;
      int off = ((row >> 5) * 2 + (g >> 1)) * 1024 +
                ((row & 31) + 32 * (g & 1)) * 16;
      *(uint4*)((char*)&kimg[0][img][0] + off) = hv;
      *(uint4*)((char*)&kimg[1][img][0] + off) = lv;
    }
  }

  float scoreacc[8];
#pragma unroll
  for (int g = 0; g < 8; ++g) scoreacc[g] = 0.f;

  for (int step = 0; step < 4; ++step) {
    const int r0 = row0 + step * 128;
    __syncthreads();
#pragma unroll
    for (int i = 0; i < 4; ++i) {
      int row = (t >> 5) + i * 8, c4 = (t & 31) * 4;
      *(float4*)&xf[row][c4] = *(const float4*)&qb[(size_t)row * Nq + r0 + c4];
    }
    __syncthreads();
#pragma unroll
    for (int i = 0; i < 2; ++i) {
      int e = t + i * 256;
      int n = e & 127, g = e >> 7;
      float v[8];
#pragma unroll
      for (int j = 0; j < 8; ++j) v[j] = xf[g * 8 + j][n];
      uint4 hv, lv;
      split8(v, hv, lv);
      int img = n >> 6, row = n & 63;
      int off = ((row >> 5) * 2 + (g >> 1)) * 1024 +
                ((row & 31) + 32 * (g & 1)) * 16;
      *(uint4*)((char*)&qimg[0][img][0] + off) = hv;
      *(uint4*)((char*)&qimg[1][img][0] + off) = lv;
    }
    __syncthreads();
    bf16x8 ah[2], al[2];
#pragma unroll
    for (int kh = 0; kh < 2; ++kh) {
      int off = ((wid & 1) * 2 + kh) * 1024 + l * 16;
      ah[kh] = *(const bf16x8*)((const char*)&qimg[0][wid >> 1][0] + off);
      al[kh] = *(const bf16x8*)((const char*)&qimg[1][wid >> 1][0] + off);
    }
    f32x16 acc[8];
#pragma unroll
    for (int g = 0; g < 8; ++g)
#pragma unroll
      for (int r = 0; r < 16; ++r) acc[g][r] = 0.f;
#pragma unroll
    for (int img = 0; img < 4; ++img)
#pragma unroll
      for (int nb = 0; nb < 2; ++nb) {
        const int g = img * 2 + nb;
#pragma unroll
        for (int kh = 0; kh < 2; ++kh) {
          int off = (nb * 2 + kh) * 1024 + l * 16;
          bf16x8 bh = *(const bf16x8*)((const char*)&kimg[0][img][0] + off);
          bf16x8 bl = *(const bf16x8*)((const char*)&kimg[1][img][0] + off);
          acc[g] = __builtin_amdgcn_mfma_f32_32x32x16_bf16(ah[kh], bh, acc[g], 0, 0, 0);
          acc[g] = __builtin_amdgcn_mfma_f32_32x32x16_bf16(ah[kh], bl, acc[g], 0, 0, 0);
          acc[g] = __builtin_amdgcn_mfma_f32_32x32x16_bf16(al[kh], bh, acc[g], 0, 0, 0);
        }
      }
    float mx[16], sm[16];
#pragma unroll
    for (int r = 0; r < 16; ++r) {
      float m = acc[0][r];
#pragma unroll
      for (int g = 1; g < 8; ++g) m = fmaxf(m, acc[g][r]);
      mx[r] = m;
    }
#pragma unroll
    for (int off = 1; off < 32; off <<= 1)
#pragma unroll
      for (int r = 0; r < 16; ++r) mx[r] = fmaxf(mx[r], __shfl_xor(mx[r], off));
#pragma unroll
    for (int r = 0; r < 16; ++r) sm[r] = 0.f;
#pragma unroll
    for (int g = 0; g < 8; ++g)
#pragma unroll
      for (int r = 0; r < 16; ++r) {
        float e = __expf((acc[g][r] - mx[r]) * SCALEq);
        acc[g][r] = e;
        sm[r] += e;
      }
#pragma unroll
    for (int off = 1; off < 32; off <<= 1)
#pragma unroll
      for (int r = 0; r < 16; ++r) sm[r] += __shfl_xor(sm[r], off);
#pragma unroll
    for (int r = 0; r < 16; ++r) sm[r] = 1.0f / sm[r];
#pragma unroll
    for (int g = 0; g < 8; ++g) {
      float tp = 0.f;
#pragma unroll
      for (int r = 0; r < 16; ++r) tp += acc[g][r] * sm[r];
      tp += __shfl_xor(tp, 32);
      scoreacc[g] += tp;
    }
  }
  if (l < 32) {
#pragma unroll
    for (int g = 0; g < 8; ++g) sc[wid][g * 32 + l] = scoreacc[g];
  }
  __syncthreads();
  {
    float v = sc[0][t] + sc[1][t] + sc[2][t] + sc[3][t];
    part[((size_t)bh * 8 + blockIdx.x) * NCq + t] = v;
  }
}

// ---------------- K3b: reduce partial scores ------------------------------
__global__ __launch_bounds__(256) void reduce_scores(
    const float* __restrict__ part, float* __restrict__ score) {
  int bh = blockIdx.x, t = threadIdx.x;
  float s = 0.f;
#pragma unroll
  for (int c = 0; c < 8; ++c) s += part[((size_t)bh * 8 + c) * NCq + t];
  score[bh * NCq + t] = s;
}

// ---------------- K4: exact stable top-64 ---------------------------------
__global__ __launch_bounds__(256) void topk_sel(
    const float* __restrict__ score, int* __restrict__ idx) {
  int bh = blockIdx.x, t = threadIdx.x;
  __shared__ float s[NCq];
  s[t] = score[bh * NCq + t];
  __syncthreads();
  float st = s[t];
  int rank = 0;
  for (int j = 0; j < NCq; ++j) {
    float sj = s[j];
    rank += (sj > st) || (sj == st && j < t);
  }
  if (rank < TOPKq) idx[bh * TOPKq + rank] = t;
}

// ---------------- K5: stage-2 attention via MFMA --------------------------
// grid (32, 64): 128 q-rows per block, one (b,h). All matmuls on matrix pipe.
__global__ __launch_bounds__(256, 2) void stage2_mfma(
    const float* __restrict__ q, const float* __restrict__ ks,
    const float* __restrict__ vs, const int* __restrict__ idx,
    char* __restrict__ at) {
  const int bh = blockIdx.y, b = bh >> 3, h = bh & 7;
  const int n0 = blockIdx.x * 128;
  const int t = threadIdx.x, l = t & 63, wid = t >> 6;
  __shared__ __align__(16) short kimg[2][2048];      // K_top B-image 64tok x 32d
  __shared__ __align__(16) short vimg[2][2][1024];   // V^T B-imgs [hi/lo][img] 32d x 32tok
  __shared__ __align__(16) short qimg[2][2][2048];   // Q A-imgs [hi/lo][img] 64row x 32d
  __shared__ float pbuf[128][66];                    // P / out round-trip
  __shared__ int ibs[64];

  const float* qb = q + ((size_t)b * Cq + h * DIMq) * Nq;
  const float* ksb = ks + ((size_t)b * Cq + h * DIMq) * NCq;
  const float* vsb = vs + ((size_t)b * Cq + h * DIMq) * NCq;
  if (t < 64) ibs[t] = idx[bh * TOPKq + t];
  __syncthreads();

  {  // K image: tok = t&63, dg = t>>6 -> 8 contiguous d
    int tok = t & 63, dg = t >> 6;
    int ti = ibs[tok];
    float v[8];
#pragma unroll
    for (int j = 0; j < 8; ++j) v[j] = ksb[(size_t)(dg * 8 + j) * NCq + ti];
    uint4 hv, lv;
    split8(v, hv, lv);
    int off = ((tok >> 5) * 2 + (dg >> 1)) * 1024 + ((tok & 31) + 32 * (dg & 1)) * 16;
    *(uint4*)((char*)&kimg[0][0] + off) = hv;
    *(uint4*)((char*)&kimg[1][0] + off) = lv;
  }
  {  // V^T images: d = l&31, tok-octet = l>>5; (t>>6) -> img, kreg
    int d = l & 31, tko = l >> 5, img = (t >> 6) >> 1, kreg = (t >> 6) & 1;
    float v[8];
#pragma unroll
    for (int j = 0; j < 8; ++j) {
      int tok = img * 32 + kreg * 16 + tko * 8 + j;
      v[j] = vsb[(size_t)d * NCq + ibs[tok]];
    }
    uint4 hv, lv;
    split8(v, hv, lv);
    int off = kreg * 1024 + (d + 32 * tko) * 16;
    *(uint4*)((char*)&vimg[0][img][0] + off) = hv;
    *(uint4*)((char*)&vimg[1][img][0] + off) = lv;
  }
#pragma unroll
  for (int qi = 0; qi < 2; ++qi) {  // Q A-images, coalesced global reads
    int qr = t & 63, dg = t >> 6;
    float v[8];
#pragma unroll
    for (int j = 0; j < 8; ++j)
      v[j] = qb[(size_t)(dg * 8 + j) * Nq + n0 + qi * 64 + qr];
    uint4 hv, lv;
    split8(v, hv, lv);
    int off = ((qr >> 5) * 2 + (dg >> 1)) * 1024 + ((qr & 31) + 32 * (dg & 1)) * 16;
    *(uint4*)((char*)&qimg[0][qi][0] + off) = hv;
    *(uint4*)((char*)&qimg[1][qi][0] + off) = lv;
  }
  __syncthreads();

  // QK^T: wave wid owns q-rows [wid*32, wid*32+32)
  f32x16 pacc[2];
#pragma unroll
  for (int g = 0; g < 2; ++g)
#pragma unroll
    for (int r = 0; r < 16; ++r) pacc[g][r] = 0.f;
  {
    bf16x8 ah[2], al[2];
#pragma unroll
    for (int kd = 0; kd < 2; ++kd) {
      int off = ((wid & 1) * 2 + kd) * 1024 + l * 16;
      ah[kd] = *(const bf16x8*)((const char*)&qimg[0][wid >> 1][0] + off);
      al[kd] = *(const bf16x8*)((const char*)&qimg[1][wid >> 1][0] + off);
    }
#pragma unroll
    for (int g = 0; g < 2; ++g)
#pragma unroll
      for (int kd = 0; kd < 2; ++kd) {
        int off = (g * 2 + kd) * 1024 + l * 16;
        bf16x8 bh = *(const bf16x8*)((const char*)&kimg[0][0] + off);
        bf16x8 bl = *(const bf16x8*)((const char*)&kimg[1][0] + off);
        pacc[g] = __builtin_amdgcn_mfma_f32_32x32x16_bf16(ah[kd], bh, pacc[g], 0, 0, 0);
        pacc[g] = __builtin_amdgcn_mfma_f32_32x32x16_bf16(ah[kd], bl, pacc[g], 0, 0, 0);
        pacc[g] = __builtin_amdgcn_mfma_f32_32x32x16_bf16(al[kd], bh, pacc[g], 0, 0, 0);
      }
  }
  // in-register softmax over the 64 selected tokens
  {
    float mx[16], sm[16];
#pragma unroll
    for (int r = 0; r < 16; ++r) mx[r] = fmaxf(pacc[0][r], pacc[1][r]);
#pragma unroll
    for (int off = 1; off < 32; off <<= 1)
#pragma unroll
      for (int r = 0; r < 16; ++r) mx[r] = fmaxf(mx[r], __shfl_xor(mx[r], off));
#pragma unroll
    for (int r = 0; r < 16; ++r) {
      float e0 = __expf((pacc[0][r] - mx[r]) * SCALEq);
      float e1 = __expf((pacc[1][r] - mx[r]) * SCALEq);
      pacc[0][r] = e0; pacc[1][r] = e1;
      sm[r] = e0 + e1;
    }
#pragma unroll
    for (int off = 1; off < 32; off <<= 1)
#pragma unroll
      for (int r = 0; r < 16; ++r) sm[r] += __shfl_xor(sm[r], off);
#pragma unroll
    for (int r = 0; r < 16; ++r) sm[r] = 1.0f / sm[r];
#pragma unroll
    for (int g = 0; g < 2; ++g)
#pragma unroll
      for (int r = 0; r < 16; ++r) {
        int qrow = wid * 32 + (r & 3) + 8 * (r >> 2) + 4 * (l >> 5);
        pbuf[qrow][g * 32 + (l & 31)] = pacc[g][r] * sm[r];
      }
  }
  __syncthreads();
  // PV: out[32 qrow][32 d] per wave; A = P (split on the fly), B = V^T images
  f32x16 oacc;
#pragma unroll
  for (int r = 0; r < 16; ++r) oacc[r] = 0.f;
#pragma unroll
  for (int ks4 = 0; ks4 < 4; ++ks4) {
    const float* pa = &pbuf[wid * 32 + (l & 31)][ks4 * 16 + (l >> 5) * 8];
    float v[8];
#pragma unroll
    for (int j = 0; j < 8; ++j) v[j] = pa[j];
    uint4 hv, lv;
    split8(v, hv, lv);
    bf16x8 pah = *(const bf16x8*)&hv, pal = *(const bf16x8*)&lv;
    int off = (ks4 & 1) * 1024 + l * 16;
    bf16x8 bh = *(const bf16x8*)((const char*)&vimg[0][ks4 >> 1][0] + off);
    bf16x8 bl = *(const bf16x8*)((const char*)&vimg[1][ks4 >> 1][0] + off);
    oacc = __builtin_amdgcn_mfma_f32_32x32x16_bf16(pah, bh, oacc, 0, 0, 0);
    oacc = __builtin_amdgcn_mfma_f32_32x32x16_bf16(pah, bl, oacc, 0, 0, 0);
    oacc = __builtin_amdgcn_mfma_f32_32x32x16_bf16(pal, bh, oacc, 0, 0, 0);
  }
  // out -> LDS (reuse pbuf; each wave overwrites only its own rows)
#pragma unroll
  for (int r = 0; r < 16; ++r) {
    int qrow = wid * 32 + (r & 3) + 8 * (r >> 2) + 4 * (l >> 5);
    pbuf[qrow][l & 31] = oacc[r];
  }
  __syncthreads();
  // final: write at hi/lo fragment images (rows 0..127 -> 2 n-blocks)
#pragma unroll
  for (int i = 0; i < 2; ++i) {
    int slot = t + i * 256;
    int row = slot >> 2, dg = slot & 3;
    float v[8];
#pragma unroll
    for (int j = 0; j < 8; ++j) v[j] = pbuf[row][dg * 8 + j];
    uint4 hv, lv;
    split8(v, hv, lv);
    int nb = blockIdx.x * 2 + (row >> 6), nloc = row & 63;
    size_t base = ((size_t)((b * 64 + nb) * 8 + h)) * 8192;
    int off = ((nloc >> 5) * 2 + (dg >> 1)) * 1024 +
              ((nloc & 31) + 32 * (dg & 1)) * 16;
    *(uint4*)(at + base + off) = hv;
    *(uint4*)(at + base + 4096 + off) = lv;
  }
}

// ---------------- K6: output projection + bias, bf16x3-split MFMA ---------
__global__ __launch_bounds__(256) void out_mfma(
    const char* __restrict__ at, const char* __restrict__ wt,
    const float* __restrict__ bo, float* __restrict__ y) {
  const int b = blockIdx.z, oblk = blockIdx.y, nblk = blockIdx.x;
  const int o0 = oblk * 64, n0 = nblk * 64;
  const int t = threadIdx.x, l = t & 63, wid = t >> 6;
  const int ob = wid >> 1, nbw = wid & 1;
  __shared__ __align__(16) short wimg[2][2048];
  __shared__ __align__(16) short ximg[2][2048];
  __shared__ float bs[64];
  if (t < 64) bs[t] = bo[o0 + t];
  f32x16 acc;
#pragma unroll
  for (int i = 0; i < 16; ++i) acc[i] = 0.f;

  for (int s = 0; s < 8; ++s) {
    __syncthreads();
    {
      const uint4* srcw = (const uint4*)(wt + ((size_t)((12 + oblk) * 8 + s)) * 8192);
      const uint4* srcx = (const uint4*)(at + ((size_t)((b * 64 + nblk) * 8 + s)) * 8192);
#pragma unroll
      for (int i = 0; i < 2; ++i) {
        ((uint4*)&wimg[0][0])[t + i * 256] = srcw[t + i * 256];
        ((uint4*)&ximg[0][0])[t + i * 256] = srcx[t + i * 256];
      }
    }
    __syncthreads();
#pragma unroll
    for (int kh = 0; kh < 2; ++kh) {
      int offa = (ob * 2 + kh) * 1024 + l * 16;
      int offb = (nbw * 2 + kh) * 1024 + l * 16;
      bf16x8 ah = *(const bf16x8*)((const char*)&wimg[0][0] + offa);
      bf16x8 al = *(const bf16x8*)((const char*)&wimg[1][0] + offa);
      bf16x8 bh = *(const bf16x8*)((const char*)&ximg[0][0] + offb);
      bf16x8 bl = *(const bf16x8*)((const char*)&ximg[1][0] + offb);
      acc = __builtin_amdgcn_mfma_f32_32x32x16_bf16(ah, bh, acc, 0, 0, 0);
      acc = __builtin_amdgcn_mfma_f32_32x32x16_bf16(ah, bl, acc, 0, 0, 0);
      acc = __builtin_amdgcn_mfma_f32_32x32x16_bf16(al, bh, acc, 0, 0, 0);
    }
  }
#pragma unroll
  for (int r = 0; r < 16; ++r) {
    int ol = ob * 32 + (r & 3) + 8 * (r >> 2) + 4 * (l >> 5);
    y[((size_t)(b * Cq + o0 + ol)) * Nq + n0 + nbw * 32 + (l & 31)] = acc[r] + bs[ol];
  }
}

extern "C" void kernel_launch(void* const* d_in, const int* in_sizes, int n_in,
                              void* d_out, int out_size, void* d_ws, size_t ws_size,
                              hipStream_t stream) {
  const float* x   = (const float*)d_in[0];
  const float* wq  = (const float*)d_in[1];
  const float* wk  = (const float*)d_in[2];
  const float* wv  = (const float*)d_in[3];
  const float* wck = (const float*)d_in[4];
  const float* wcv = (const float*)d_in[5];
  const float* wo  = (const float*)d_in[6];
  const float* bo  = (const float*)d_in[7];
  float* out = (float*)d_out;

  float* ws = (float*)d_ws;
  const size_t SZ_FULL = (size_t)Bq * Cq * Nq;   // 8388608
  const size_t SZ_CMP  = (size_t)Bq * Cq * NCq;  // 524288
  float* q     = ws;
  float* kf    = q  + SZ_FULL;
  float* vf    = kf + SZ_FULL;
  float* ksc   = vf + SZ_FULL;
  float* vsc   = ksc + SZ_CMP;
  float* part  = vsc + SZ_CMP;
  float* score = part + (size_t)BHq * 8 * NCq;
  int*   idx   = (int*)(score + (size_t)BHq * NCq);
  char*  wt    = (char*)(idx + (size_t)BHq * TOPKq);  // 1MB weight images
  char*  at    = (char*)kf;  // reuse: kf dead after pool_kv

  prep_w<<<dim3(4, 8, 4), 256, 0, stream>>>(wq, wk, wv, wo, wt);
  qkv_mfma<<<dim3(64, 4, 8), 256, 0, stream>>>(x, wt, q, kf, vf);
  pool_kv<<<dim3(Bq * Cq), 256, 0, stream>>>(kf, vf, wck, wcv, ksc, vsc);
  stage1_mfma<<<dim3(8, BHq), 256, 0, stream>>>(q, ksc, part);
  reduce_scores<<<dim3(BHq), 256, 0, stream>>>(part, score);
  topk_sel<<<dim3(BHq), 256, 0, stream>>>(score, idx);
  stage2_mfma<<<dim3(32, BHq), 256, 0, stream>>>(q, ksc, vsc, idx, at);
  out_mfma<<<dim3(64, 4, 8), 256, 0, stream>>>(at, wt, bo, out);
}